// Round 1
// baseline (3093.542 us; speedup 1.0000x reference)
//
#include <hip/hip_runtime.h>

typedef unsigned short u16;
typedef unsigned int u32;

#define B_GRAPHS 128
#define N_NODES  512
#define D_DIM    256
#define E_EDGES  8192
#define K_TOP    410

typedef __attribute__((ext_vector_type(8))) __bf16 bf16x8;
typedef __attribute__((ext_vector_type(4))) float  f32x4;

__device__ __forceinline__ float bf2f(u16 h) {
  union { u32 u; float f; } c; c.u = ((u32)h) << 16; return c.f;
}
__device__ __forceinline__ u16 f2bf(float f) {
  union { float f; u32 u; } c; c.f = f;
  u32 u = c.u;
  u += 0x7fffu + ((u >> 16) & 1u);   // round-to-nearest-even
  return (u16)(u >> 16);
}

// ---------------------------------------------------------------- prep ------
// WT layout: [mat][n][k] bf16, mat in {Wr2, Ws2, Wr3, Ws3}
__global__ void prep_kernel(const float* __restrict__ Wr2, const float* __restrict__ Ws2,
                            const float* __restrict__ Wr3, const float* __restrict__ Ws3,
                            u16* __restrict__ WT) {
  const int mat = blockIdx.y;
  const int n = blockIdx.x;
  const int k = threadIdx.x;
  const float* W = (mat == 0) ? Wr2 : (mat == 1) ? Ws2 : (mat == 2) ? Wr3 : Ws3;
  WT[((size_t)mat << 16) + ((size_t)n << 8) + k] = f2bf(W[(size_t)k * 256 + n]);
}

// ---------------------------------------------------------------- conv1 -----
// One block per graph. K=4 input dim: direct LDS scatter + fused matmul/relu
// + fused max/mean pooling (x1).
__global__ void conv1_kernel(const float* __restrict__ x, const int* __restrict__ src,
                             const int* __restrict__ dst,
                             const float* __restrict__ Wr1, const float* __restrict__ Ws1,
                             const float* __restrict__ b1,
                             u16* __restrict__ H1, float* __restrict__ X1) {
  __shared__ float xs[N_NODES * 5];    // padded stride 5
  __shared__ float aggs[N_NODES * 5];
  const int g = blockIdx.x;
  const int base = g * N_NODES;
  const int t = threadIdx.x;           // 256 threads

  for (int i = t; i < N_NODES; i += 256) {
    const float4 v = *(const float4*)&x[(size_t)(base + i) * 4];
    xs[i * 5 + 0] = v.x; xs[i * 5 + 1] = v.y; xs[i * 5 + 2] = v.z; xs[i * 5 + 3] = v.w;
    aggs[i * 5 + 0] = 0.f; aggs[i * 5 + 1] = 0.f; aggs[i * 5 + 2] = 0.f; aggs[i * 5 + 3] = 0.f;
  }
  __syncthreads();
  const int ebase = g * E_EDGES;
  for (int e = t; e < E_EDGES; e += 256) {
    const int s = src[ebase + e] - base;
    const int d = dst[ebase + e] - base;
    #pragma unroll
    for (int k = 0; k < 4; ++k) atomicAdd(&aggs[d * 5 + k], xs[s * 5 + k]);
  }
  __syncthreads();
  // thread t = output feature
  float wr[4], ws[4];
  #pragma unroll
  for (int k = 0; k < 4; ++k) { wr[k] = Wr1[k * 256 + t]; ws[k] = Ws1[k * 256 + t]; }
  const float bb = b1[t];
  float mx = -1e30f, sm = 0.f;
  for (int n = 0; n < N_NODES; ++n) {
    float acc = bb;
    #pragma unroll
    for (int k = 0; k < 4; ++k) acc += aggs[n * 5 + k] * wr[k] + xs[n * 5 + k] * ws[k];
    acc = fmaxf(acc, 0.f);
    H1[(size_t)(base + n) * D_DIM + t] = f2bf(acc);
    mx = fmaxf(mx, acc);
    sm += acc;
  }
  X1[(size_t)g * 512 + t] = mx;
  X1[(size_t)g * 512 + 256 + t] = sm * (1.f / 512.f);
}

// ---------------------------------------------------------------- agg -------
// Block (c, g): graph g, feature chunk c (32 features). h chunk staged bf16 in
// LDS; fp32 accumulator padded to stride 33 (conflict-free LDS atomics).
__global__ __launch_bounds__(512) void agg_kernel(const u16* __restrict__ H,
                                                  const int* __restrict__ src,
                                                  const int* __restrict__ dst,
                                                  u16* __restrict__ AGG) {
  __shared__ __align__(16) u16 hs[N_NODES * 32];   // 32 KB
  __shared__ float aggs[N_NODES * 33];             // 67.6 KB
  const int c = blockIdx.x;     // 0..7
  const int g = blockIdx.y;
  const int base = g * N_NODES;
  const int t = threadIdx.x;    // 512 threads

  #pragma unroll
  for (int p = 0; p < 4; ++p) {
    const int idx = p * 512 + t;
    const int row = idx >> 2, q = idx & 3;
    *(uint4*)&hs[row * 32 + q * 8] =
        *(const uint4*)&H[(size_t)(base + row) * D_DIM + c * 32 + q * 8];
  }
  for (int i = t; i < N_NODES * 33; i += 512) aggs[i] = 0.f;
  __syncthreads();

  const int j = t & 31;
  const int slot = t >> 5;          // 0..15
  const int ebase = g * E_EDGES + slot;
  #pragma unroll 4
  for (int it = 0; it < 512; ++it) {
    const int e = ebase + it * 16;
    const int s = src[e] - base;
    const int d = dst[e] - base;
    atomicAdd(&aggs[d * 33 + j], bf2f(hs[s * 32 + j]));
  }
  __syncthreads();

  #pragma unroll
  for (int p = 0; p < 4; ++p) {
    const int idx = p * 512 + t;
    const int row = idx >> 2, q = idx & 3;
    u16 __align__(16) o8[8];
    #pragma unroll
    for (int i = 0; i < 8; ++i) o8[i] = f2bf(aggs[row * 33 + q * 8 + i]);
    *(uint4*)&AGG[(size_t)(base + row) * D_DIM + c * 32 + q * 8] = *(const uint4*)o8;
  }
}

// ---------------------------------------------------------------- gemm ------
// Hout = relu(Amat @ Wr + Hmat @ Ws + bias), all [65536 x 256] bf16,
// WrT/WsT stored transposed [n][k] bf16. 128x128 tile, 4 waves (2x2),
// mfma_f32_16x16x32_bf16, XOR chunk swizzle on LDS tiles.
__global__ __launch_bounds__(256) void gemm_kernel(const u16* __restrict__ Amat,
                                                   const u16* __restrict__ Hmat,
                                                   const u16* __restrict__ WrT,
                                                   const u16* __restrict__ WsT,
                                                   const float* __restrict__ bias,
                                                   u16* __restrict__ Hout) {
  __shared__ __align__(16) u16 At[128 * 32];
  __shared__ __align__(16) u16 Bt[128 * 32];
  const int m0 = blockIdx.x * 128;
  const int n0 = blockIdx.y * 128;
  const int t = threadIdx.x;
  const int wid = t >> 6, lane = t & 63;
  const int wm = wid >> 1, wn = wid & 1;
  const int r16 = lane & 15, q0 = lane >> 4;

  f32x4 acc[4][4];
  const f32x4 zero = {0.f, 0.f, 0.f, 0.f};
  #pragma unroll
  for (int i = 0; i < 4; ++i)
    #pragma unroll
    for (int jj = 0; jj < 4; ++jj) acc[i][jj] = zero;

  const int srow = t >> 2, sq = t & 3;
  const int sqs = sq ^ ((srow >> 1) & 3);   // same swizzle for row and row+64

  #pragma unroll 1
  for (int ph = 0; ph < 2; ++ph) {
    const u16* Ain = ph ? Hmat : Amat;
    const u16* Win = ph ? WsT : WrT;
    #pragma unroll 1
    for (int kk = 0; kk < 256; kk += 32) {
      __syncthreads();
      *(uint4*)&At[srow * 32 + sqs * 8] =
          *(const uint4*)&Ain[(size_t)(m0 + srow) * 256 + kk + sq * 8];
      *(uint4*)&At[(srow + 64) * 32 + sqs * 8] =
          *(const uint4*)&Ain[(size_t)(m0 + srow + 64) * 256 + kk + sq * 8];
      *(uint4*)&Bt[srow * 32 + sqs * 8] =
          *(const uint4*)&Win[(size_t)(n0 + srow) * 256 + kk + sq * 8];
      *(uint4*)&Bt[(srow + 64) * 32 + sqs * 8] =
          *(const uint4*)&Win[(size_t)(n0 + srow + 64) * 256 + kk + sq * 8];
      __syncthreads();
      bf16x8 aF[4], bF[4];
      #pragma unroll
      for (int mi = 0; mi < 4; ++mi) {
        const int arow = wm * 64 + mi * 16 + r16;
        const int qs = q0 ^ ((arow >> 1) & 3);
        aF[mi] = *(const bf16x8*)&At[arow * 32 + qs * 8];
      }
      #pragma unroll
      for (int ni = 0; ni < 4; ++ni) {
        const int brow = wn * 64 + ni * 16 + r16;
        const int qs = q0 ^ ((brow >> 1) & 3);
        bF[ni] = *(const bf16x8*)&Bt[brow * 32 + qs * 8];
      }
      #pragma unroll
      for (int mi = 0; mi < 4; ++mi)
        #pragma unroll
        for (int ni = 0; ni < 4; ++ni)
          acc[mi][ni] = __builtin_amdgcn_mfma_f32_16x16x32_bf16(aF[mi], bF[ni],
                                                                acc[mi][ni], 0, 0, 0);
    }
  }
  // epilogue: C/D layout col = lane&15, row = (lane>>4)*4 + reg  [m89]
  #pragma unroll
  for (int mi = 0; mi < 4; ++mi) {
    const int growb = m0 + wm * 64 + mi * 16 + q0 * 4;
    #pragma unroll
    for (int ni = 0; ni < 4; ++ni) {
      const int gcol = n0 + wn * 64 + ni * 16 + r16;
      const float bv = bias[gcol];
      #pragma unroll
      for (int r = 0; r < 4; ++r) {
        float v = acc[mi][ni][r] + bv;
        v = fmaxf(v, 0.f);
        Hout[(size_t)(growb + r) * 256 + gcol] = f2bf(v);
      }
    }
  }
}

// ---------------------------------------------------------------- pool ------
__global__ void pool_kernel(const u16* __restrict__ H, float* __restrict__ X) {
  const int g = blockIdx.x, t = threadIdx.x;
  const size_t base = (size_t)g * N_NODES;
  float mx = -1e30f, sm = 0.f;
  for (int n = 0; n < N_NODES; ++n) {
    const float v = bf2f(H[(base + n) * D_DIM + t]);
    mx = fmaxf(mx, v); sm += v;
  }
  X[(size_t)g * 512 + t] = mx;
  X[(size_t)g * 512 + 256 + t] = sm * (1.f / 512.f);
}

// ---------------------------------------------------------------- topk ------
__global__ void topk_kernel(const u16* __restrict__ H3, const float* __restrict__ p,
                            float* __restrict__ X3) {
  __shared__ float sval[N_NODES];
  __shared__ int sidx[N_NODES];
  __shared__ float sscale[K_TOP];
  const int g = blockIdx.x, t = threadIdx.x;
  const size_t base = (size_t)g * N_NODES;

  float n2 = 0.f;
  for (int d = 0; d < 256; ++d) { const float pv = p[d]; n2 += pv * pv; }
  const float pn = sqrtf(n2) + 1e-16f;

  const int wid = t >> 6, l = t & 63;
  for (int n = wid; n < N_NODES; n += 4) {
    float dv = 0.f;
    #pragma unroll
    for (int cc = 0; cc < 4; ++cc) {
      const int d = cc * 64 + l;
      dv += bf2f(H3[(base + n) * D_DIM + d]) * p[d];
    }
    #pragma unroll
    for (int off = 32; off > 0; off >>= 1) dv += __shfl_down(dv, off);
    if (l == 0) { sval[n] = dv / pn; sidx[n] = n; }
  }
  __syncthreads();

  // bitonic sort, descending, tie-break: lower index first (jax top_k)
  for (int k = 2; k <= N_NODES; k <<= 1) {
    for (int jj = k >> 1; jj > 0; jj >>= 1) {
      const int i = ((t & ~(jj - 1)) << 1) | (t & (jj - 1));
      const int ix = i | jj;
      const bool dirDesc = ((i & k) == 0);
      const float vi = sval[i], vx = sval[ix];
      const int ii = sidx[i], ij = sidx[ix];
      const bool iAfter = (vi < vx) || (vi == vx && ii > ij);
      if (dirDesc ? iAfter : !iAfter) {
        sval[i] = vx; sval[ix] = vi;
        sidx[i] = ij; sidx[ix] = ii;
      }
      __syncthreads();
    }
  }

  for (int s2 = t; s2 < K_TOP; s2 += 256) sscale[s2] = tanhf(sval[s2]);
  __syncthreads();

  float mx = -1e30f, sm = 0.f;
  for (int s2 = 0; s2 < K_TOP; ++s2) {
    const int row = sidx[s2];
    const float v = bf2f(H3[(base + row) * D_DIM + t]) * sscale[s2];
    mx = fmaxf(mx, v); sm += v;
  }
  X3[(size_t)g * 512 + t] = mx;
  X3[(size_t)g * 512 + 256 + t] = sm * (1.f / (float)K_TOP);
}

// ---------------------------------------------------------------- mlp -------
__global__ void mlp_kernel(const float* __restrict__ X1, const float* __restrict__ X2,
                           const float* __restrict__ X3,
                           const float* __restrict__ W1, const float* __restrict__ c1,
                           const float* __restrict__ W2, const float* __restrict__ c2,
                           const float* __restrict__ W3, const float* __restrict__ c3,
                           float* __restrict__ out) {
  __shared__ float zs[512];
  __shared__ float z1[256];
  __shared__ float z2[128];
  const int g = blockIdx.x, t = threadIdx.x;
  for (int k = t; k < 512; k += 256)
    zs[k] = X1[(size_t)g * 512 + k] + X2[(size_t)g * 512 + k] + X3[(size_t)g * 512 + k];
  __syncthreads();
  {
    float acc = c1[t];
    for (int k = 0; k < 512; ++k) acc += zs[k] * W1[(size_t)k * 256 + t];
    z1[t] = fmaxf(acc, 0.f);
  }
  __syncthreads();
  if (t < 128) {
    float acc = c2[t];
    for (int d = 0; d < 256; ++d) acc += z1[d] * W2[(size_t)d * 128 + t];
    z2[t] = fmaxf(acc, 0.f);
  }
  __syncthreads();
  if (t == 0) {
    float acc = c3[0];
    for (int e = 0; e < 128; ++e) acc += z2[e] * W3[e];
    out[g] = 1.f / (1.f + expf(-acc));
  }
}

// ---------------------------------------------------------------- launch ----
extern "C" void kernel_launch(void* const* d_in, const int* in_sizes, int n_in,
                              void* d_out, int out_size, void* d_ws, size_t ws_size,
                              hipStream_t stream) {
  (void)in_sizes; (void)n_in; (void)out_size; (void)ws_size;
  const float* x   = (const float*)d_in[0];
  const int* src   = (const int*)d_in[1];
  const int* dstp  = (const int*)d_in[2];
  const float* Wr1 = (const float*)d_in[3];
  const float* Ws1 = (const float*)d_in[4];
  const float* b1  = (const float*)d_in[5];
  const float* Wr2 = (const float*)d_in[6];
  const float* Ws2 = (const float*)d_in[7];
  const float* b2  = (const float*)d_in[8];
  const float* Wr3 = (const float*)d_in[9];
  const float* Ws3 = (const float*)d_in[10];
  const float* b3  = (const float*)d_in[11];
  const float* pat = (const float*)d_in[12];
  const float* W1  = (const float*)d_in[13];
  const float* c1  = (const float*)d_in[14];
  const float* W2  = (const float*)d_in[15];
  const float* c2  = (const float*)d_in[16];
  const float* W3  = (const float*)d_in[17];
  const float* c3  = (const float*)d_in[18];
  float* out = (float*)d_out;

  char* ws = (char*)d_ws;
  u16* hA  = (u16*)(ws);                 // 32 MB  (h1, later h3)
  u16* hB  = (u16*)(ws + 33554432);      // 32 MB  (h2)
  u16* AGG = (u16*)(ws + 67108864);      // 32 MB
  u16* WT  = (u16*)(ws + 100663296);     // 512 KB (4 x 256x256 bf16, transposed)
  float* x1 = (float*)(ws + 101187584);  // 256 KB
  float* x2 = (float*)(ws + 101449728);  // 256 KB
  float* x3 = (float*)(ws + 101711872);  // 256 KB

  prep_kernel<<<dim3(256, 4), dim3(256), 0, stream>>>(Wr2, Ws2, Wr3, Ws3, WT);
  conv1_kernel<<<dim3(128), dim3(256), 0, stream>>>(x, src, dstp, Wr1, Ws1, b1, hA, x1);

  agg_kernel<<<dim3(8, 128), dim3(512), 0, stream>>>(hA, src, dstp, AGG);
  gemm_kernel<<<dim3(512, 2), dim3(256), 0, stream>>>(AGG, hA, WT, WT + 65536, b2, hB);
  pool_kernel<<<dim3(128), dim3(256), 0, stream>>>(hB, x2);

  agg_kernel<<<dim3(8, 128), dim3(512), 0, stream>>>(hB, src, dstp, AGG);
  gemm_kernel<<<dim3(512, 2), dim3(256), 0, stream>>>(AGG, hB, WT + 131072, WT + 196608, b3, hA);

  topk_kernel<<<dim3(128), dim3(256), 0, stream>>>(hA, pat, x3);
  mlp_kernel<<<dim3(128), dim3(256), 0, stream>>>(x1, x2, x3, W1, c1, W2, c2, W3, c3, out);
}

// Round 2
// 406.675 us; speedup vs baseline: 7.6069x; 7.6069x over previous
//
#include <hip/hip_runtime.h>

typedef unsigned short u16;
typedef unsigned int u32;

#define B_GRAPHS 128
#define N_NODES  512
#define D_DIM    256
#define E_EDGES  8192
#define K_TOP    410

typedef __attribute__((ext_vector_type(8))) __bf16 bf16x8;
typedef __attribute__((ext_vector_type(4))) float  f32x4;

__device__ __forceinline__ float bf2f(u16 h) {
  union { u32 u; float f; } c; c.u = ((u32)h) << 16; return c.f;
}
__device__ __forceinline__ float u2f(u32 u) {
  union { u32 u; float f; } c; c.u = u; return c.f;
}
__device__ __forceinline__ u16 f2bf(float f) {
  union { float f; u32 u; } c; c.f = f;
  u32 u = c.u;
  u += 0x7fffu + ((u >> 16) & 1u);   // round-to-nearest-even
  return (u16)(u >> 16);
}

// ---------------------------------------------------------------- prep ------
// WT layout: [mat][n][k] bf16, mat in {Wr2, Ws2, Wr3, Ws3}
__global__ void prep_kernel(const float* __restrict__ Wr2, const float* __restrict__ Ws2,
                            const float* __restrict__ Wr3, const float* __restrict__ Ws3,
                            u16* __restrict__ WT) {
  const int mat = blockIdx.y;
  const int n = blockIdx.x;
  const int k = threadIdx.x;
  const float* W = (mat == 0) ? Wr2 : (mat == 1) ? Ws2 : (mat == 2) ? Wr3 : Ws3;
  WT[((size_t)mat << 16) + ((size_t)n << 8) + k] = f2bf(W[(size_t)k * 256 + n]);
}

// ---------------------------------------------------------------- csr -------
// Per-graph CSR build: dst -> list of src (local ids, u16). One block/graph.
// Scalar LDS atomics (~16K lane-ops/graph) - one-time cost.
__global__ __launch_bounds__(256) void csr_kernel(const int* __restrict__ src,
                                                  const int* __restrict__ dst,
                                                  u16* __restrict__ csr_col,
                                                  u32* __restrict__ csr_off) {
  __shared__ u32 cnt[512];
  __shared__ u32 offs[513];
  const int g = blockIdx.x, t = threadIdx.x;
  const int base = g * N_NODES, ebase = g * E_EDGES;
  for (int i = t; i < 512; i += 256) cnt[i] = 0;
  __syncthreads();
  for (int e = t; e < E_EDGES; e += 256)
    atomicAdd(&cnt[dst[ebase + e] - base], 1u);
  __syncthreads();
  if (t == 0) {
    u32 run = 0;
    for (int i = 0; i < 512; ++i) { offs[i] = run; run += cnt[i]; }
    offs[512] = run;
  }
  __syncthreads();
  for (int i = t; i < 513; i += 256) csr_off[(size_t)g * 513 + i] = offs[i];
  for (int i = t; i < 512; i += 256) cnt[i] = offs[i];
  __syncthreads();
  for (int e = t; e < E_EDGES; e += 256) {
    const int d = dst[ebase + e] - base;
    const int s = src[ebase + e] - base;
    const u32 pos = atomicAdd(&cnt[d], 1u);
    csr_col[(size_t)g * E_EDGES + pos] = (u16)s;
  }
}

// ---------------------------------------------------------------- conv1 -----
// One block per graph. CSR gather (no atomics) + fused matmul/relu + x1 pool.
__global__ __launch_bounds__(256) void conv1_kernel(const float* __restrict__ x,
                             const u16* __restrict__ csr_col, const u32* __restrict__ csr_off,
                             const float* __restrict__ Wr1, const float* __restrict__ Ws1,
                             const float* __restrict__ b1,
                             u16* __restrict__ H1, float* __restrict__ X1) {
  __shared__ float xs[N_NODES * 4];    // float4 per node
  __shared__ float aggs[N_NODES * 5];  // stride 5 for broadcast phase
  __shared__ u16 cols[E_EDGES];
  __shared__ u32 offs[513];
  const int g = blockIdx.x;
  const int base = g * N_NODES;
  const int t = threadIdx.x;           // 256 threads

  for (int i = t; i < N_NODES; i += 256)
    *(float4*)&xs[i * 4] = *(const float4*)&x[(size_t)(base + i) * 4];
  for (int i = t; i < E_EDGES / 2; i += 256)
    ((u32*)cols)[i] = ((const u32*)(csr_col + (size_t)g * E_EDGES))[i];
  for (int i = t; i < 513; i += 256) offs[i] = csr_off[(size_t)g * 513 + i];
  __syncthreads();

  // gather: thread t handles dst nodes 2t, 2t+1
  #pragma unroll
  for (int nn = 0; nn < 2; ++nn) {
    const int i = t * 2 + nn;
    const u32 s0 = offs[i], s1 = offs[i + 1];
    float a0 = 0.f, a1 = 0.f, a2 = 0.f, a3 = 0.f;
    for (u32 k = s0; k < s1; ++k) {
      const int col = cols[k];
      const float4 v = *(const float4*)&xs[col * 4];
      a0 += v.x; a1 += v.y; a2 += v.z; a3 += v.w;
    }
    aggs[i * 5 + 0] = a0; aggs[i * 5 + 1] = a1;
    aggs[i * 5 + 2] = a2; aggs[i * 5 + 3] = a3;
  }
  __syncthreads();

  // thread t = output feature
  float wr[4], wsv[4];
  #pragma unroll
  for (int k = 0; k < 4; ++k) { wr[k] = Wr1[k * 256 + t]; wsv[k] = Ws1[k * 256 + t]; }
  const float bb = b1[t];
  float mx = -1e30f, sm = 0.f;
  for (int n = 0; n < N_NODES; ++n) {
    float acc = bb;
    #pragma unroll
    for (int k = 0; k < 4; ++k) acc += aggs[n * 5 + k] * wr[k] + xs[n * 4 + k] * wsv[k];
    acc = fmaxf(acc, 0.f);
    H1[(size_t)(base + n) * D_DIM + t] = f2bf(acc);
    mx = fmaxf(mx, acc);
    sm += acc;
  }
  X1[(size_t)g * 512 + t] = mx;
  X1[(size_t)g * 512 + 256 + t] = sm * (1.f / 512.f);
}

// ---------------------------------------------------------------- agg -------
// Gather-based segment_sum: block (c,g) stages h[g][:, c*128:(c+1)*128] in LDS
// (row stride 136 u16 to spread banks), wave w owns dst rows [w*64,(w+1)*64),
// half-waves process edge pairs, fp32 accum in regs, shfl_xor(32) combine.
// No atomics.
#define HS_STRIDE 136
__global__ __launch_bounds__(512) void agg_gather_kernel(const u16* __restrict__ H,
                                                         const u16* __restrict__ csr_col,
                                                         const u32* __restrict__ csr_off,
                                                         u16* __restrict__ AGG) {
  __shared__ __align__(16) u16 hs[N_NODES * HS_STRIDE];  // 139264 B
  __shared__ u16 cols[E_EDGES];                          // 16384 B
  __shared__ u32 offs[513];                              // 2052 B
  const int c = blockIdx.x;          // 0..1 feature chunk (128 feats)
  const int g = blockIdx.y;
  const int base = g * N_NODES;
  const int t = threadIdx.x;         // 512 threads

  // stage h chunk: 512 rows x 128 bf16, uint4 (8 bf16) per slot
  #pragma unroll
  for (int p = 0; p < 16; ++p) {
    const int flat = p * 512 + t;
    const int row = flat >> 4, q = flat & 15;
    *(uint4*)&hs[row * HS_STRIDE + q * 8] =
        *(const uint4*)&H[(size_t)(base + row) * D_DIM + c * 128 + q * 8];
  }
  const u32* colsw = (const u32*)(csr_col + (size_t)g * E_EDGES);
  #pragma unroll
  for (int p = 0; p < 8; ++p) ((u32*)cols)[p * 512 + t] = colsw[p * 512 + t];
  for (int i = t; i < 513; i += 512) offs[i] = csr_off[(size_t)g * 513 + i];
  __syncthreads();

  const int w = t >> 6, lane = t & 63;
  const int h2 = lane >> 5, fl = lane & 31;   // half-wave, feature-lane
  const int i0 = w * 64;
  for (int i = i0; i < i0 + 64; ++i) {
    const u32 s0 = offs[i], s1 = offs[i + 1];
    float a0 = 0.f, a1 = 0.f, a2 = 0.f, a3 = 0.f;
    for (u32 k = s0 + h2; k < s1; k += 2) {
      const int col = cols[k];
      const uint2 dd = *(const uint2*)&hs[col * HS_STRIDE + fl * 4];
      a0 += u2f(dd.x << 16);
      a1 += u2f(dd.x & 0xffff0000u);
      a2 += u2f(dd.y << 16);
      a3 += u2f(dd.y & 0xffff0000u);
    }
    a0 += __shfl_xor(a0, 32);
    a1 += __shfl_xor(a1, 32);
    a2 += __shfl_xor(a2, 32);
    a3 += __shfl_xor(a3, 32);
    if (h2 == 0) {
      uint2 o;
      o.x = (u32)f2bf(a0) | ((u32)f2bf(a1) << 16);
      o.y = (u32)f2bf(a2) | ((u32)f2bf(a3) << 16);
      *(uint2*)&AGG[(size_t)(base + i) * D_DIM + c * 128 + fl * 4] = o;
    }
  }
}

// ---------------------------------------------------------------- gemm ------
// Hout = relu(Amat @ Wr + Hmat @ Ws + bias), all [65536 x 256] bf16,
// WrT/WsT stored transposed [n][k] bf16. 128x128 tile, 4 waves (2x2),
// mfma_f32_16x16x32_bf16, XOR chunk swizzle on LDS tiles.
__global__ __launch_bounds__(256) void gemm_kernel(const u16* __restrict__ Amat,
                                                   const u16* __restrict__ Hmat,
                                                   const u16* __restrict__ WrT,
                                                   const u16* __restrict__ WsT,
                                                   const float* __restrict__ bias,
                                                   u16* __restrict__ Hout) {
  __shared__ __align__(16) u16 At[128 * 32];
  __shared__ __align__(16) u16 Bt[128 * 32];
  const int m0 = blockIdx.x * 128;
  const int n0 = blockIdx.y * 128;
  const int t = threadIdx.x;
  const int wid = t >> 6, lane = t & 63;
  const int wm = wid >> 1, wn = wid & 1;
  const int r16 = lane & 15, q0 = lane >> 4;

  f32x4 acc[4][4];
  const f32x4 zero = {0.f, 0.f, 0.f, 0.f};
  #pragma unroll
  for (int i = 0; i < 4; ++i)
    #pragma unroll
    for (int jj = 0; jj < 4; ++jj) acc[i][jj] = zero;

  const int srow = t >> 2, sq = t & 3;
  const int sqs = sq ^ ((srow >> 1) & 3);   // same swizzle for row and row+64

  #pragma unroll 1
  for (int ph = 0; ph < 2; ++ph) {
    const u16* Ain = ph ? Hmat : Amat;
    const u16* Win = ph ? WsT : WrT;
    #pragma unroll 1
    for (int kk = 0; kk < 256; kk += 32) {
      __syncthreads();
      *(uint4*)&At[srow * 32 + sqs * 8] =
          *(const uint4*)&Ain[(size_t)(m0 + srow) * 256 + kk + sq * 8];
      *(uint4*)&At[(srow + 64) * 32 + sqs * 8] =
          *(const uint4*)&Ain[(size_t)(m0 + srow + 64) * 256 + kk + sq * 8];
      *(uint4*)&Bt[srow * 32 + sqs * 8] =
          *(const uint4*)&Win[(size_t)(n0 + srow) * 256 + kk + sq * 8];
      *(uint4*)&Bt[(srow + 64) * 32 + sqs * 8] =
          *(const uint4*)&Win[(size_t)(n0 + srow + 64) * 256 + kk + sq * 8];
      __syncthreads();
      bf16x8 aF[4], bF[4];
      #pragma unroll
      for (int mi = 0; mi < 4; ++mi) {
        const int arow = wm * 64 + mi * 16 + r16;
        const int qs = q0 ^ ((arow >> 1) & 3);
        aF[mi] = *(const bf16x8*)&At[arow * 32 + qs * 8];
      }
      #pragma unroll
      for (int ni = 0; ni < 4; ++ni) {
        const int brow = wn * 64 + ni * 16 + r16;
        const int qs = q0 ^ ((brow >> 1) & 3);
        bF[ni] = *(const bf16x8*)&Bt[brow * 32 + qs * 8];
      }
      #pragma unroll
      for (int mi = 0; mi < 4; ++mi)
        #pragma unroll
        for (int ni = 0; ni < 4; ++ni)
          acc[mi][ni] = __builtin_amdgcn_mfma_f32_16x16x32_bf16(aF[mi], bF[ni],
                                                                acc[mi][ni], 0, 0, 0);
    }
  }
  // epilogue: C/D layout col = lane&15, row = (lane>>4)*4 + reg  [m89]
  #pragma unroll
  for (int mi = 0; mi < 4; ++mi) {
    const int growb = m0 + wm * 64 + mi * 16 + q0 * 4;
    #pragma unroll
    for (int ni = 0; ni < 4; ++ni) {
      const int gcol = n0 + wn * 64 + ni * 16 + r16;
      const float bv = bias[gcol];
      #pragma unroll
      for (int r = 0; r < 4; ++r) {
        float v = acc[mi][ni][r] + bv;
        v = fmaxf(v, 0.f);
        Hout[(size_t)(growb + r) * 256 + gcol] = f2bf(v);
      }
    }
  }
}

// ---------------------------------------------------------------- pool ------
__global__ void pool_kernel(const u16* __restrict__ H, float* __restrict__ X) {
  const int g = blockIdx.x, t = threadIdx.x;
  const size_t base = (size_t)g * N_NODES;
  float mx = -1e30f, sm = 0.f;
  for (int n = 0; n < N_NODES; ++n) {
    const float v = bf2f(H[(base + n) * D_DIM + t]);
    mx = fmaxf(mx, v); sm += v;
  }
  X[(size_t)g * 512 + t] = mx;
  X[(size_t)g * 512 + 256 + t] = sm * (1.f / 512.f);
}

// ---------------------------------------------------------------- topk ------
__global__ void topk_kernel(const u16* __restrict__ H3, const float* __restrict__ p,
                            float* __restrict__ X3) {
  __shared__ float sval[N_NODES];
  __shared__ int sidx[N_NODES];
  __shared__ float sscale[K_TOP];
  const int g = blockIdx.x, t = threadIdx.x;
  const size_t base = (size_t)g * N_NODES;

  float n2 = 0.f;
  for (int d = 0; d < 256; ++d) { const float pv = p[d]; n2 += pv * pv; }
  const float pn = sqrtf(n2) + 1e-16f;

  const int wid = t >> 6, l = t & 63;
  for (int n = wid; n < N_NODES; n += 4) {
    float dv = 0.f;
    #pragma unroll
    for (int cc = 0; cc < 4; ++cc) {
      const int d = cc * 64 + l;
      dv += bf2f(H3[(base + n) * D_DIM + d]) * p[d];
    }
    #pragma unroll
    for (int off = 32; off > 0; off >>= 1) dv += __shfl_down(dv, off);
    if (l == 0) { sval[n] = dv / pn; sidx[n] = n; }
  }
  __syncthreads();

  // bitonic sort, descending, tie-break: lower index first (jax top_k)
  for (int k = 2; k <= N_NODES; k <<= 1) {
    for (int jj = k >> 1; jj > 0; jj >>= 1) {
      const int i = ((t & ~(jj - 1)) << 1) | (t & (jj - 1));
      const int ix = i | jj;
      const bool dirDesc = ((i & k) == 0);
      const float vi = sval[i], vx = sval[ix];
      const int ii = sidx[i], ij = sidx[ix];
      const bool iAfter = (vi < vx) || (vi == vx && ii > ij);
      if (dirDesc ? iAfter : !iAfter) {
        sval[i] = vx; sval[ix] = vi;
        sidx[i] = ij; sidx[ix] = ii;
      }
      __syncthreads();
    }
  }

  for (int s2 = t; s2 < K_TOP; s2 += 256) sscale[s2] = tanhf(sval[s2]);
  __syncthreads();

  float mx = -1e30f, sm = 0.f;
  for (int s2 = 0; s2 < K_TOP; ++s2) {
    const int row = sidx[s2];
    const float v = bf2f(H3[(base + row) * D_DIM + t]) * sscale[s2];
    mx = fmaxf(mx, v); sm += v;
  }
  X3[(size_t)g * 512 + t] = mx;
  X3[(size_t)g * 512 + 256 + t] = sm * (1.f / (float)K_TOP);
}

// ---------------------------------------------------------------- mlp -------
__global__ void mlp_kernel(const float* __restrict__ X1, const float* __restrict__ X2,
                           const float* __restrict__ X3,
                           const float* __restrict__ W1, const float* __restrict__ c1,
                           const float* __restrict__ W2, const float* __restrict__ c2,
                           const float* __restrict__ W3, const float* __restrict__ c3,
                           float* __restrict__ out) {
  __shared__ float zs[512];
  __shared__ float z1[256];
  __shared__ float z2[128];
  const int g = blockIdx.x, t = threadIdx.x;
  for (int k = t; k < 512; k += 256)
    zs[k] = X1[(size_t)g * 512 + k] + X2[(size_t)g * 512 + k] + X3[(size_t)g * 512 + k];
  __syncthreads();
  {
    float acc = c1[t];
    for (int k = 0; k < 512; ++k) acc += zs[k] * W1[(size_t)k * 256 + t];
    z1[t] = fmaxf(acc, 0.f);
  }
  __syncthreads();
  if (t < 128) {
    float acc = c2[t];
    for (int d = 0; d < 256; ++d) acc += z1[d] * W2[(size_t)d * 128 + t];
    z2[t] = fmaxf(acc, 0.f);
  }
  __syncthreads();
  if (t == 0) {
    float acc = c3[0];
    for (int e = 0; e < 128; ++e) acc += z2[e] * W3[e];
    out[g] = 1.f / (1.f + expf(-acc));
  }
}

// ---------------------------------------------------------------- launch ----
extern "C" void kernel_launch(void* const* d_in, const int* in_sizes, int n_in,
                              void* d_out, int out_size, void* d_ws, size_t ws_size,
                              hipStream_t stream) {
  (void)in_sizes; (void)n_in; (void)out_size; (void)ws_size;
  const float* x   = (const float*)d_in[0];
  const int* src   = (const int*)d_in[1];
  const int* dstp  = (const int*)d_in[2];
  const float* Wr1 = (const float*)d_in[3];
  const float* Ws1 = (const float*)d_in[4];
  const float* b1  = (const float*)d_in[5];
  const float* Wr2 = (const float*)d_in[6];
  const float* Ws2 = (const float*)d_in[7];
  const float* b2  = (const float*)d_in[8];
  const float* Wr3 = (const float*)d_in[9];
  const float* Ws3 = (const float*)d_in[10];
  const float* b3  = (const float*)d_in[11];
  const float* pat = (const float*)d_in[12];
  const float* W1  = (const float*)d_in[13];
  const float* c1  = (const float*)d_in[14];
  const float* W2  = (const float*)d_in[15];
  const float* c2  = (const float*)d_in[16];
  const float* W3  = (const float*)d_in[17];
  const float* c3  = (const float*)d_in[18];
  float* out = (float*)d_out;

  char* ws = (char*)d_ws;
  u16* hA  = (u16*)(ws);                 // 32 MB  (h1, later h3)
  u16* hB  = (u16*)(ws + 33554432);      // 32 MB  (h2)
  u16* AGG = (u16*)(ws + 67108864);      // 32 MB
  u16* WT  = (u16*)(ws + 100663296);     // 512 KB (4 x 256x256 bf16, transposed)
  float* x1 = (float*)(ws + 101187584);  // 256 KB
  float* x2 = (float*)(ws + 101449728);  // 256 KB
  float* x3 = (float*)(ws + 101711872);  // 256 KB
  u16* csr_col = (u16*)(ws + 101974016); // 2 MB   (per-graph src lists, u16 local ids)
  u32* csr_off = (u32*)(ws + 104071168); // 263 KB (per-graph 513 offsets)

  prep_kernel<<<dim3(256, 4), dim3(256), 0, stream>>>(Wr2, Ws2, Wr3, Ws3, WT);
  csr_kernel<<<dim3(128), dim3(256), 0, stream>>>(src, dstp, csr_col, csr_off);
  conv1_kernel<<<dim3(128), dim3(256), 0, stream>>>(x, csr_col, csr_off, Wr1, Ws1, b1, hA, x1);

  agg_gather_kernel<<<dim3(2, 128), dim3(512), 0, stream>>>(hA, csr_col, csr_off, AGG);
  gemm_kernel<<<dim3(512, 2), dim3(256), 0, stream>>>(AGG, hA, WT, WT + 65536, b2, hB);
  pool_kernel<<<dim3(128), dim3(256), 0, stream>>>(hB, x2);

  agg_gather_kernel<<<dim3(2, 128), dim3(512), 0, stream>>>(hB, csr_col, csr_off, AGG);
  gemm_kernel<<<dim3(512, 2), dim3(256), 0, stream>>>(AGG, hB, WT + 131072, WT + 196608, b3, hA);

  topk_kernel<<<dim3(128), dim3(256), 0, stream>>>(hA, pat, x3);
  mlp_kernel<<<dim3(128), dim3(256), 0, stream>>>(x1, x2, x3, W1, c1, W2, c2, W3, c3, out);
}

// Round 3
// 319.934 us; speedup vs baseline: 9.6693x; 1.2711x over previous
//
#include <hip/hip_runtime.h>

typedef unsigned short u16;
typedef unsigned int u32;

#define B_GRAPHS 128
#define N_NODES  512
#define D_DIM    256
#define E_EDGES  8192
#define K_TOP    410

typedef __attribute__((ext_vector_type(8))) __bf16 bf16x8;
typedef __attribute__((ext_vector_type(4))) float  f32x4;

__device__ __forceinline__ float bf2f(u16 h) {
  union { u32 u; float f; } c; c.u = ((u32)h) << 16; return c.f;
}
__device__ __forceinline__ float u2f(u32 u) {
  union { u32 u; float f; } c; c.u = u; return c.f;
}
__device__ __forceinline__ u16 f2bf(float f) {
  union { float f; u32 u; } c; c.f = f;
  u32 u = c.u;
  u += 0x7fffu + ((u >> 16) & 1u);   // round-to-nearest-even
  return (u16)(u >> 16);
}

// ---------------------------------------------------------------- zero ------
__global__ void zero_kernel(float* __restrict__ p) {
  *(float4*)&p[(size_t)(blockIdx.x * 256 + threadIdx.x) * 4] = float4{0.f, 0.f, 0.f, 0.f};
}

// ---------------------------------------------------------------- prep ------
// WT layout: [mat][n][k] bf16, mat in {Wr2, Ws2, Wr3, Ws3}
__global__ void prep_kernel(const float* __restrict__ Wr2, const float* __restrict__ Ws2,
                            const float* __restrict__ Wr3, const float* __restrict__ Ws3,
                            u16* __restrict__ WT) {
  const int mat = blockIdx.y;
  const int n = blockIdx.x;
  const int k = threadIdx.x;
  const float* W = (mat == 0) ? Wr2 : (mat == 1) ? Ws2 : (mat == 2) ? Wr3 : Ws3;
  WT[((size_t)mat << 16) + ((size_t)n << 8) + k] = f2bf(W[(size_t)k * 256 + n]);
}

// ---------------------------------------------------------------- csr -------
__global__ __launch_bounds__(256) void csr_kernel(const int* __restrict__ src,
                                                  const int* __restrict__ dst,
                                                  u16* __restrict__ csr_col,
                                                  u32* __restrict__ csr_off) {
  __shared__ u32 cnt[512];
  __shared__ u32 offs[513];
  const int g = blockIdx.x, t = threadIdx.x;
  const int base = g * N_NODES, ebase = g * E_EDGES;
  for (int i = t; i < 512; i += 256) cnt[i] = 0;
  __syncthreads();
  for (int e = t; e < E_EDGES; e += 256)
    atomicAdd(&cnt[dst[ebase + e] - base], 1u);
  __syncthreads();
  if (t == 0) {
    u32 run = 0;
    for (int i = 0; i < 512; ++i) { offs[i] = run; run += cnt[i]; }
    offs[512] = run;
  }
  __syncthreads();
  for (int i = t; i < 513; i += 256) csr_off[(size_t)g * 513 + i] = offs[i];
  for (int i = t; i < 512; i += 256) cnt[i] = offs[i];
  __syncthreads();
  for (int e = t; e < E_EDGES; e += 256) {
    const int d = dst[ebase + e] - base;
    const int s = src[ebase + e] - base;
    const u32 pos = atomicAdd(&cnt[d], 1u);
    csr_col[(size_t)g * E_EDGES + pos] = (u16)s;
  }
}

// ---------------------------------------------------------------- conv1 -----
__global__ __launch_bounds__(256) void conv1_kernel(const float* __restrict__ x,
                             const u16* __restrict__ csr_col, const u32* __restrict__ csr_off,
                             const float* __restrict__ Wr1, const float* __restrict__ Ws1,
                             const float* __restrict__ b1,
                             u16* __restrict__ H1, float* __restrict__ X1) {
  __shared__ float xs[N_NODES * 4];
  __shared__ float aggs[N_NODES * 5];
  __shared__ u16 cols[E_EDGES];
  __shared__ u32 offs[513];
  const int g = blockIdx.x;
  const int base = g * N_NODES;
  const int t = threadIdx.x;           // 256 threads

  for (int i = t; i < N_NODES; i += 256)
    *(float4*)&xs[i * 4] = *(const float4*)&x[(size_t)(base + i) * 4];
  for (int i = t; i < E_EDGES / 2; i += 256)
    ((u32*)cols)[i] = ((const u32*)(csr_col + (size_t)g * E_EDGES))[i];
  for (int i = t; i < 513; i += 256) offs[i] = csr_off[(size_t)g * 513 + i];
  __syncthreads();

  #pragma unroll
  for (int nn = 0; nn < 2; ++nn) {
    const int i = t * 2 + nn;
    const u32 s0 = offs[i], s1 = offs[i + 1];
    float a0 = 0.f, a1 = 0.f, a2 = 0.f, a3 = 0.f;
    for (u32 k = s0; k < s1; ++k) {
      const int col = cols[k];
      const float4 v = *(const float4*)&xs[col * 4];
      a0 += v.x; a1 += v.y; a2 += v.z; a3 += v.w;
    }
    aggs[i * 5 + 0] = a0; aggs[i * 5 + 1] = a1;
    aggs[i * 5 + 2] = a2; aggs[i * 5 + 3] = a3;
  }
  __syncthreads();

  float wr[4], wsv[4];
  #pragma unroll
  for (int k = 0; k < 4; ++k) { wr[k] = Wr1[k * 256 + t]; wsv[k] = Ws1[k * 256 + t]; }
  const float bb = b1[t];
  float mx = -1e30f, sm = 0.f;
  for (int n = 0; n < N_NODES; ++n) {
    float acc = bb;
    #pragma unroll
    for (int k = 0; k < 4; ++k) acc += aggs[n * 5 + k] * wr[k] + xs[n * 4 + k] * wsv[k];
    acc = fmaxf(acc, 0.f);
    H1[(size_t)(base + n) * D_DIM + t] = f2bf(acc);
    mx = fmaxf(mx, acc);
    sm += acc;
  }
  X1[(size_t)g * 512 + t] = mx;
  X1[(size_t)g * 512 + 256 + t] = sm * (1.f / 512.f);
}

// ---------------------------------------------------------------- agg -------
#define HS_STRIDE 136
__global__ __launch_bounds__(512) void agg_gather_kernel(const u16* __restrict__ H,
                                                         const u16* __restrict__ csr_col,
                                                         const u32* __restrict__ csr_off,
                                                         u16* __restrict__ AGG) {
  __shared__ __align__(16) u16 hs[N_NODES * HS_STRIDE];
  __shared__ u16 cols[E_EDGES];
  __shared__ u32 offs[513];
  const int c = blockIdx.x;
  const int g = blockIdx.y;
  const int base = g * N_NODES;
  const int t = threadIdx.x;

  #pragma unroll
  for (int p = 0; p < 16; ++p) {
    const int flat = p * 512 + t;
    const int row = flat >> 4, q = flat & 15;
    *(uint4*)&hs[row * HS_STRIDE + q * 8] =
        *(const uint4*)&H[(size_t)(base + row) * D_DIM + c * 128 + q * 8];
  }
  const u32* colsw = (const u32*)(csr_col + (size_t)g * E_EDGES);
  #pragma unroll
  for (int p = 0; p < 8; ++p) ((u32*)cols)[p * 512 + t] = colsw[p * 512 + t];
  for (int i = t; i < 513; i += 512) offs[i] = csr_off[(size_t)g * 513 + i];
  __syncthreads();

  const int w = t >> 6, lane = t & 63;
  const int h2 = lane >> 5, fl = lane & 31;
  const int i0 = w * 64;
  for (int i = i0; i < i0 + 64; ++i) {
    const u32 s0 = offs[i], s1 = offs[i + 1];
    float a0 = 0.f, a1 = 0.f, a2 = 0.f, a3 = 0.f;
    for (u32 k = s0 + h2; k < s1; k += 2) {
      const int col = cols[k];
      const uint2 dd = *(const uint2*)&hs[col * HS_STRIDE + fl * 4];
      a0 += u2f(dd.x << 16);
      a1 += u2f(dd.x & 0xffff0000u);
      a2 += u2f(dd.y << 16);
      a3 += u2f(dd.y & 0xffff0000u);
    }
    a0 += __shfl_xor(a0, 32);
    a1 += __shfl_xor(a1, 32);
    a2 += __shfl_xor(a2, 32);
    a3 += __shfl_xor(a3, 32);
    if (h2 == 0) {
      uint2 o;
      o.x = (u32)f2bf(a0) | ((u32)f2bf(a1) << 16);
      o.y = (u32)f2bf(a2) | ((u32)f2bf(a3) << 16);
      *(uint2*)&AGG[(size_t)(base + i) * D_DIM + c * 128 + fl * 4] = o;
    }
  }
}

// ---------------------------------------------------------------- gemm ------
// Hout = relu(Amat @ Wr + Hmat @ Ws + bias). Optional fused epilogues:
//   x2pool != null : per-graph column max/sum pooling (atomicMax/Add)
//   score  != null : per-row dot with pvec (atomicAdd partials)
__global__ __launch_bounds__(256) void gemm_kernel(const u16* __restrict__ Amat,
                                                   const u16* __restrict__ Hmat,
                                                   const u16* __restrict__ WrT,
                                                   const u16* __restrict__ WsT,
                                                   const float* __restrict__ bias,
                                                   u16* __restrict__ Hout,
                                                   float* __restrict__ x2pool,
                                                   float* __restrict__ score,
                                                   const float* __restrict__ pvec) {
  __shared__ __align__(16) u16 At[128 * 32];
  __shared__ __align__(16) u16 Bt[128 * 32];
  const int m0 = blockIdx.x * 128;
  const int n0 = blockIdx.y * 128;
  const int t = threadIdx.x;
  const int wid = t >> 6, lane = t & 63;
  const int wm = wid >> 1, wn = wid & 1;
  const int r16 = lane & 15, q0 = lane >> 4;

  f32x4 acc[4][4];
  const f32x4 zero = {0.f, 0.f, 0.f, 0.f};
  #pragma unroll
  for (int i = 0; i < 4; ++i)
    #pragma unroll
    for (int jj = 0; jj < 4; ++jj) acc[i][jj] = zero;

  const int srow = t >> 2, sq = t & 3;
  const int sqs = sq ^ ((srow >> 1) & 3);

  #pragma unroll 1
  for (int ph = 0; ph < 2; ++ph) {
    const u16* Ain = ph ? Hmat : Amat;
    const u16* Win = ph ? WsT : WrT;
    #pragma unroll 1
    for (int kk = 0; kk < 256; kk += 32) {
      __syncthreads();
      *(uint4*)&At[srow * 32 + sqs * 8] =
          *(const uint4*)&Ain[(size_t)(m0 + srow) * 256 + kk + sq * 8];
      *(uint4*)&At[(srow + 64) * 32 + sqs * 8] =
          *(const uint4*)&Ain[(size_t)(m0 + srow + 64) * 256 + kk + sq * 8];
      *(uint4*)&Bt[srow * 32 + sqs * 8] =
          *(const uint4*)&Win[(size_t)(n0 + srow) * 256 + kk + sq * 8];
      *(uint4*)&Bt[(srow + 64) * 32 + sqs * 8] =
          *(const uint4*)&Win[(size_t)(n0 + srow + 64) * 256 + kk + sq * 8];
      __syncthreads();
      bf16x8 aF[4], bF[4];
      #pragma unroll
      for (int mi = 0; mi < 4; ++mi) {
        const int arow = wm * 64 + mi * 16 + r16;
        const int qs = q0 ^ ((arow >> 1) & 3);
        aF[mi] = *(const bf16x8*)&At[arow * 32 + qs * 8];
      }
      #pragma unroll
      for (int ni = 0; ni < 4; ++ni) {
        const int brow = wn * 64 + ni * 16 + r16;
        const int qs = q0 ^ ((brow >> 1) & 3);
        bF[ni] = *(const bf16x8*)&Bt[brow * 32 + qs * 8];
      }
      #pragma unroll
      for (int mi = 0; mi < 4; ++mi)
        #pragma unroll
        for (int ni = 0; ni < 4; ++ni)
          acc[mi][ni] = __builtin_amdgcn_mfma_f32_16x16x32_bf16(aF[mi], bF[ni],
                                                                acc[mi][ni], 0, 0, 0);
    }
  }

  const bool do_x2 = (x2pool != nullptr);
  const bool do_sc = (score != nullptr);
  float colmax[4], colsum[4], pv[4], rpart[4][4];
  #pragma unroll
  for (int ni = 0; ni < 4; ++ni) { colmax[ni] = 0.f; colsum[ni] = 0.f; pv[ni] = 0.f; }
  #pragma unroll
  for (int mi = 0; mi < 4; ++mi)
    #pragma unroll
    for (int r = 0; r < 4; ++r) rpart[mi][r] = 0.f;
  if (do_sc) {
    #pragma unroll
    for (int ni = 0; ni < 4; ++ni) pv[ni] = pvec[n0 + wn * 64 + ni * 16 + r16];
  }

  // epilogue: C/D layout col = lane&15, row = (lane>>4)*4 + reg  [m89]
  #pragma unroll
  for (int mi = 0; mi < 4; ++mi) {
    const int growb = m0 + wm * 64 + mi * 16 + q0 * 4;
    #pragma unroll
    for (int ni = 0; ni < 4; ++ni) {
      const int gcol = n0 + wn * 64 + ni * 16 + r16;
      const float bv = bias[gcol];
      #pragma unroll
      for (int r = 0; r < 4; ++r) {
        float v = acc[mi][ni][r] + bv;
        v = fmaxf(v, 0.f);
        Hout[(size_t)(growb + r) * 256 + gcol] = f2bf(v);
        colmax[ni] = fmaxf(colmax[ni], v);
        colsum[ni] += v;
        rpart[mi][r] += v * pv[ni];
      }
    }
  }

  const int gg = m0 >> 9;   // graph index (128-row tile never straddles a graph)
  if (do_x2) {
    #pragma unroll
    for (int ni = 0; ni < 4; ++ni) {
      const int gcol = n0 + wn * 64 + ni * 16 + r16;
      float cm = colmax[ni], cs = colsum[ni];
      cm = fmaxf(cm, __shfl_xor(cm, 16));
      cm = fmaxf(cm, __shfl_xor(cm, 32));
      cs += __shfl_xor(cs, 16);
      cs += __shfl_xor(cs, 32);
      if (q0 == 0) {
        atomicMax((int*)&x2pool[(size_t)gg * 512 + gcol], __float_as_int(cm));
        atomicAdd(&x2pool[(size_t)gg * 512 + 256 + gcol], cs);
      }
    }
  }
  if (do_sc) {
    #pragma unroll
    for (int mi = 0; mi < 4; ++mi) {
      const int growb = m0 + wm * 64 + mi * 16 + q0 * 4;
      #pragma unroll
      for (int r = 0; r < 4; ++r) {
        float sp = rpart[mi][r];
        sp += __shfl_xor(sp, 1);
        sp += __shfl_xor(sp, 2);
        sp += __shfl_xor(sp, 4);
        sp += __shfl_xor(sp, 8);
        if (r16 == 0) atomicAdd(&score[growb + r], sp);
      }
    }
  }
}

// ---------------------------------------------------------------- sort ------
// One block/graph: normalize scores, bitonic sort (desc, tie low-idx), emit
// top-410 index + tanh-scale lists.
__global__ __launch_bounds__(256) void sort_kernel(const float* __restrict__ score,
                                                   const float* __restrict__ p,
                                                   u16* __restrict__ top_idx,
                                                   float* __restrict__ top_scale) {
  __shared__ float sval[N_NODES];
  __shared__ int sidx[N_NODES];
  __shared__ float wsum[4];
  const int g = blockIdx.x, t = threadIdx.x;

  // ||p||^2 via wave reduce
  float pvt = p[t];
  float sq = pvt * pvt;
  #pragma unroll
  for (int off = 32; off > 0; off >>= 1) sq += __shfl_down(sq, off);
  if ((t & 63) == 0) wsum[t >> 6] = sq;
  __syncthreads();
  const float inv_pn = 1.f / (sqrtf(wsum[0] + wsum[1] + wsum[2] + wsum[3]) + 1e-16f);

  for (int n = t; n < N_NODES; n += 256) {
    sval[n] = score[(size_t)g * 512 + n] * inv_pn;
    sidx[n] = n;
  }
  __syncthreads();

  for (int k = 2; k <= N_NODES; k <<= 1) {
    for (int jj = k >> 1; jj > 0; jj >>= 1) {
      const int i = ((t & ~(jj - 1)) << 1) | (t & (jj - 1));
      const int ix = i | jj;
      const bool dirDesc = ((i & k) == 0);
      const float vi = sval[i], vx = sval[ix];
      const int ii = sidx[i], ij = sidx[ix];
      const bool iAfter = (vi < vx) || (vi == vx && ii > ij);
      if (dirDesc ? iAfter : !iAfter) {
        sval[i] = vx; sval[ix] = vi;
        sidx[i] = ij; sidx[ix] = ii;
      }
      __syncthreads();
    }
  }

  for (int s = t; s < K_TOP; s += 256) {
    top_idx[(size_t)g * 416 + s] = (u16)sidx[s];
    top_scale[(size_t)g * 416 + s] = tanhf(sval[s]);
  }
}

// ---------------------------------------------------------------- x3 pool ---
// Block (c,g): graph g, feature chunk c (64 feats). 32-way row split, 16B
// loads, stride-65 LDS tree reduce.
__global__ __launch_bounds__(256) void x3_pool_kernel(const u16* __restrict__ H3,
                                                      const u16* __restrict__ top_idx,
                                                      const float* __restrict__ top_scale,
                                                      float* __restrict__ X3) {
  __shared__ u16 sidxL[416];
  __shared__ float ssclL[416];
  __shared__ float redm[32 * 65];
  __shared__ float reds[32 * 65];
  const int c = blockIdx.x;          // 0..3
  const int g = blockIdx.y;
  const int t = threadIdx.x;
  const int fl = t & 7, rg = t >> 3;

  for (int s = t; s < K_TOP; s += 256) {
    sidxL[s] = top_idx[(size_t)g * 416 + s];
    ssclL[s] = top_scale[(size_t)g * 416 + s];
  }
  __syncthreads();

  float mx[8], sm[8];
  #pragma unroll
  for (int j = 0; j < 8; ++j) { mx[j] = -1e30f; sm[j] = 0.f; }
  const size_t rowbase = (size_t)g * 512;
  for (int s = rg; s < K_TOP; s += 32) {
    const int row = sidxL[s];
    const float sc = ssclL[s];
    const uint4 d = *(const uint4*)&H3[(rowbase + row) * 256 + c * 64 + fl * 8];
    const u32 wv[4] = {d.x, d.y, d.z, d.w};
    #pragma unroll
    for (int q = 0; q < 4; ++q) {
      const float v0 = u2f(wv[q] << 16) * sc;
      const float v1 = u2f(wv[q] & 0xffff0000u) * sc;
      mx[q * 2] = fmaxf(mx[q * 2], v0); sm[q * 2] += v0;
      mx[q * 2 + 1] = fmaxf(mx[q * 2 + 1], v1); sm[q * 2 + 1] += v1;
    }
  }
  #pragma unroll
  for (int j = 0; j < 8; ++j) {
    redm[rg * 65 + fl * 8 + j] = mx[j];
    reds[rg * 65 + fl * 8 + j] = sm[j];
  }
  __syncthreads();
  for (int st = 16; st >= 1; st >>= 1) {
    if (rg < st) {
      #pragma unroll
      for (int j = 0; j < 8; ++j) {
        const int a = rg * 65 + fl * 8 + j, b = (rg + st) * 65 + fl * 8 + j;
        redm[a] = fmaxf(redm[a], redm[b]);
        reds[a] += reds[b];
      }
    }
    __syncthreads();
  }
  if (rg == 0) {
    #pragma unroll
    for (int j = 0; j < 8; ++j) {
      X3[(size_t)g * 512 + c * 64 + fl * 8 + j] = redm[fl * 8 + j];
      X3[(size_t)g * 512 + 256 + c * 64 + fl * 8 + j] = reds[fl * 8 + j] * (1.f / (float)K_TOP);
    }
  }
}

// ---------------------------------------------------------------- mlp -------
__global__ void mlp_kernel(const float* __restrict__ X1, const float* __restrict__ X2,
                           const float* __restrict__ X3,
                           const float* __restrict__ W1, const float* __restrict__ c1,
                           const float* __restrict__ W2, const float* __restrict__ c2,
                           const float* __restrict__ W3, const float* __restrict__ c3,
                           float* __restrict__ out) {
  __shared__ float zs[512];
  __shared__ float z1[256];
  __shared__ float z2[128];
  const int g = blockIdx.x, t = threadIdx.x;
  for (int k = t; k < 512; k += 256) {
    const float x2v = X2[(size_t)g * 512 + k];
    zs[k] = X1[(size_t)g * 512 + k] + (k < 256 ? x2v : x2v * (1.f / 512.f))
          + X3[(size_t)g * 512 + k];
  }
  __syncthreads();
  {
    float acc = c1[t];
    for (int k = 0; k < 512; ++k) acc += zs[k] * W1[(size_t)k * 256 + t];
    z1[t] = fmaxf(acc, 0.f);
  }
  __syncthreads();
  if (t < 128) {
    float acc = c2[t];
    for (int d = 0; d < 256; ++d) acc += z1[d] * W2[(size_t)d * 128 + t];
    z2[t] = fmaxf(acc, 0.f);
  }
  __syncthreads();
  if (t == 0) {
    float acc = c3[0];
    for (int e = 0; e < 128; ++e) acc += z2[e] * W3[e];
    out[g] = 1.f / (1.f + expf(-acc));
  }
}

// ---------------------------------------------------------------- launch ----
extern "C" void kernel_launch(void* const* d_in, const int* in_sizes, int n_in,
                              void* d_out, int out_size, void* d_ws, size_t ws_size,
                              hipStream_t stream) {
  (void)in_sizes; (void)n_in; (void)out_size; (void)ws_size;
  const float* x   = (const float*)d_in[0];
  const int* src   = (const int*)d_in[1];
  const int* dstp  = (const int*)d_in[2];
  const float* Wr1 = (const float*)d_in[3];
  const float* Ws1 = (const float*)d_in[4];
  const float* b1  = (const float*)d_in[5];
  const float* Wr2 = (const float*)d_in[6];
  const float* Ws2 = (const float*)d_in[7];
  const float* b2  = (const float*)d_in[8];
  const float* Wr3 = (const float*)d_in[9];
  const float* Ws3 = (const float*)d_in[10];
  const float* b3  = (const float*)d_in[11];
  const float* pat = (const float*)d_in[12];
  const float* W1  = (const float*)d_in[13];
  const float* c1  = (const float*)d_in[14];
  const float* W2  = (const float*)d_in[15];
  const float* c2  = (const float*)d_in[16];
  const float* W3  = (const float*)d_in[17];
  const float* c3  = (const float*)d_in[18];
  float* out = (float*)d_out;

  char* ws = (char*)d_ws;
  u16* hA  = (u16*)(ws);                 // 32 MB  (h1, later h3)
  u16* hB  = (u16*)(ws + 33554432);      // 32 MB  (h2)
  u16* AGG = (u16*)(ws + 67108864);      // 32 MB
  u16* WT  = (u16*)(ws + 100663296);     // 512 KB
  float* x1 = (float*)(ws + 101187584);  // 256 KB
  float* x2 = (float*)(ws + 101449728);  // 256 KB
  float* x3 = (float*)(ws + 101711872);  // 256 KB
  u16* csr_col = (u16*)(ws + 101974016); // 2 MB (dead after agg#2 -> reused below)
  u32* csr_off = (u32*)(ws + 104071168); // ~1 MB
  // aliases into csr_col slot (only used after agg#2 completes):
  float* score     = (float*)(ws + 101974016);            // 256 KB
  u16* top_idx     = (u16*)(ws + 101974016 + 262144);     // 104 KB
  float* top_scale = (float*)(ws + 101974016 + 372736);   // 208 KB

  prep_kernel<<<dim3(256, 4), dim3(256), 0, stream>>>(Wr2, Ws2, Wr3, Ws3, WT);
  csr_kernel<<<dim3(128), dim3(256), 0, stream>>>(src, dstp, csr_col, csr_off);
  zero_kernel<<<dim3(64), dim3(256), 0, stream>>>(x2);
  conv1_kernel<<<dim3(128), dim3(256), 0, stream>>>(x, csr_col, csr_off, Wr1, Ws1, b1, hA, x1);

  agg_gather_kernel<<<dim3(2, 128), dim3(512), 0, stream>>>(hA, csr_col, csr_off, AGG);
  gemm_kernel<<<dim3(512, 2), dim3(256), 0, stream>>>(AGG, hA, WT, WT + 65536, b2, hB,
                                                      x2, nullptr, nullptr);

  agg_gather_kernel<<<dim3(2, 128), dim3(512), 0, stream>>>(hB, csr_col, csr_off, AGG);
  zero_kernel<<<dim3(64), dim3(256), 0, stream>>>(score);
  gemm_kernel<<<dim3(512, 2), dim3(256), 0, stream>>>(AGG, hB, WT + 131072, WT + 196608, b3, hA,
                                                      nullptr, score, pat);

  sort_kernel<<<dim3(128), dim3(256), 0, stream>>>(score, pat, top_idx, top_scale);
  x3_pool_kernel<<<dim3(4, 128), dim3(256), 0, stream>>>(hA, top_idx, top_scale, x3);
  mlp_kernel<<<dim3(128), dim3(256), 0, stream>>>(x1, x2, x3, W1, c1, W2, c2, W3, c3, out);
}

// Round 4
// 283.501 us; speedup vs baseline: 10.9119x; 1.1285x over previous
//
#include <hip/hip_runtime.h>

typedef unsigned short u16;
typedef unsigned int u32;

#define B_GRAPHS 128
#define N_NODES  512
#define D_DIM    256
#define E_EDGES  8192
#define K_TOP    410
#define CSR_STRIDE 12288   // padded per-graph edge-list capacity (8-aligned rows)
#define AS 132             // hs row stride in u16 (8B-aligned for uint2 ops)

typedef __attribute__((ext_vector_type(8))) __bf16 bf16x8;
typedef __attribute__((ext_vector_type(4))) float  f32x4;

__device__ __forceinline__ float bf2f(u16 h) {
  union { u32 u; float f; } c; c.u = ((u32)h) << 16; return c.f;
}
__device__ __forceinline__ float u2f(u32 u) {
  union { u32 u; float f; } c; c.u = u; return c.f;
}
__device__ __forceinline__ u16 f2bf(float f) {
  union { float f; u32 u; } c; c.f = f;
  u32 u = c.u;
  u += 0x7fffu + ((u >> 16) & 1u);   // round-to-nearest-even
  return (u16)(u >> 16);
}
__device__ __forceinline__ void async_copy16(const void* g, void* l) {
  __builtin_amdgcn_global_load_lds((const __attribute__((address_space(1))) void*)g,
                                   (__attribute__((address_space(3))) void*)l, 16, 0, 0);
}

// ---------------------------------------------------------------- zero ------
__global__ void zero_kernel(float* __restrict__ p) {
  *(float4*)&p[(size_t)(blockIdx.x * 256 + threadIdx.x) * 4] = float4{0.f, 0.f, 0.f, 0.f};
}

// ---------------------------------------------------------------- prep ------
// WT layout: [mat][n][k] bf16, mat in {Wr2, Ws2, Wr3, Ws3}
__global__ void prep_kernel(const float* __restrict__ Wr2, const float* __restrict__ Ws2,
                            const float* __restrict__ Wr3, const float* __restrict__ Ws3,
                            u16* __restrict__ WT) {
  const int mat = blockIdx.y;
  const int n = blockIdx.x;
  const int k = threadIdx.x;
  const float* W = (mat == 0) ? Wr2 : (mat == 1) ? Ws2 : (mat == 2) ? Wr3 : Ws3;
  WT[((size_t)mat << 16) + ((size_t)n << 8) + k] = f2bf(W[(size_t)k * 256 + n]);
}

// ---------------------------------------------------------------- csr -------
// Per-graph CSR, rows padded to multiples of 8 with dummy col 512 (zero row).
__global__ __launch_bounds__(256) void csr_kernel(const int* __restrict__ src,
                                                  const int* __restrict__ dst,
                                                  u16* __restrict__ csr_col,
                                                  u32* __restrict__ csr_off) {
  __shared__ u32 cnt[512];
  __shared__ u32 poff[513];
  const int g = blockIdx.x, t = threadIdx.x;
  const int base = g * N_NODES, ebase = g * E_EDGES;
  for (int i = t; i < 512; i += 256) cnt[i] = 0;
  __syncthreads();
  for (int e = t; e < E_EDGES; e += 256)
    atomicAdd(&cnt[dst[ebase + e] - base], 1u);
  __syncthreads();
  if (t == 0) {
    u32 run = 0;
    for (int i = 0; i < 512; ++i) { poff[i] = run; run += (cnt[i] + 7u) & ~7u; }
    poff[512] = run;
  }
  __syncthreads();
  for (int i = t; i < 513; i += 256) csr_off[(size_t)g * 513 + i] = poff[i];
  // fill pad slots with the zero-row col
  for (int i = t; i < 512; i += 256) {
    const u32 s = poff[i] + cnt[i], e2 = poff[i + 1];
    for (u32 k = s; k < e2; ++k) csr_col[(size_t)g * CSR_STRIDE + k] = 512;
  }
  __syncthreads();
  for (int i = t; i < 512; i += 256) cnt[i] = poff[i];
  __syncthreads();
  for (int e = t; e < E_EDGES; e += 256) {
    const int d = dst[ebase + e] - base;
    const int s = src[ebase + e] - base;
    const u32 pos = atomicAdd(&cnt[d], 1u);
    csr_col[(size_t)g * CSR_STRIDE + pos] = (u16)s;
  }
}

// ---------------------------------------------------------------- conv1 -----
// Block (c,g): graph g, node half c (256 nodes). Gather duplicated per block
// (batched 8-col reads), matmul+relu+H1 for its node half, x1 pool via atomics.
__global__ __launch_bounds__(256) void conv1_kernel(const float* __restrict__ x,
                             const u16* __restrict__ csr_col, const u32* __restrict__ csr_off,
                             const float* __restrict__ Wr1, const float* __restrict__ Ws1,
                             const float* __restrict__ b1,
                             u16* __restrict__ H1, float* __restrict__ X1) {
  __shared__ float xs[513 * 4];        // +zero row 512
  __shared__ float aggs[N_NODES * 5];
  __shared__ __align__(16) u16 cols[CSR_STRIDE];
  __shared__ u32 offs[513];
  const int c = blockIdx.x;            // node half 0/1
  const int g = blockIdx.y;
  const int base = g * N_NODES;
  const int t = threadIdx.x;           // 256 threads

  for (int i = t; i < N_NODES; i += 256)
    *(float4*)&xs[i * 4] = *(const float4*)&x[(size_t)(base + i) * 4];
  if (t < 4) xs[512 * 4 + t] = 0.f;
  for (int i = t; i < CSR_STRIDE / 2; i += 256)
    ((u32*)cols)[i] = ((const u32*)(csr_col + (size_t)g * CSR_STRIDE))[i];
  for (int i = t; i < 513; i += 256) offs[i] = csr_off[(size_t)g * 513 + i];
  __syncthreads();

  // gather (all 512 rows; 2 per thread), 8-col batches
  #pragma unroll
  for (int nn = 0; nn < 2; ++nn) {
    const int i = t * 2 + nn;
    const u32 s0 = offs[i];
    const int nb = (int)((offs[i + 1] - s0) >> 3);
    float a0 = 0.f, a1 = 0.f, a2 = 0.f, a3 = 0.f;
    for (int b = 0; b < nb; ++b) {
      const uint4 cw = *(const uint4*)&cols[s0 + (u32)b * 8];
      const u32 ww[4] = {cw.x, cw.y, cw.z, cw.w};
      #pragma unroll
      for (int q = 0; q < 4; ++q) {
        const int ca = ww[q] & 0xffffu, cb = ww[q] >> 16;
        const float4 va = *(const float4*)&xs[ca * 4];
        const float4 vb = *(const float4*)&xs[cb * 4];
        a0 += va.x + vb.x; a1 += va.y + vb.y;
        a2 += va.z + vb.z; a3 += va.w + vb.w;
      }
    }
    aggs[i * 5 + 0] = a0; aggs[i * 5 + 1] = a1;
    aggs[i * 5 + 2] = a2; aggs[i * 5 + 3] = a3;
  }
  __syncthreads();

  // matmul over this block's 256 nodes; thread t = output feature
  float wr[4], wsv[4];
  #pragma unroll
  for (int k = 0; k < 4; ++k) { wr[k] = Wr1[k * 256 + t]; wsv[k] = Ws1[k * 256 + t]; }
  const float bb = b1[t];
  float mx = 0.f, sm = 0.f;   // relu => >= 0
  const int nlo = c * 256;
  for (int n = nlo; n < nlo + 256; ++n) {
    float acc = bb;
    #pragma unroll
    for (int k = 0; k < 4; ++k) acc += aggs[n * 5 + k] * wr[k] + xs[n * 4 + k] * wsv[k];
    acc = fmaxf(acc, 0.f);
    H1[(size_t)(base + n) * D_DIM + t] = f2bf(acc);
    mx = fmaxf(mx, acc);
    sm += acc;
  }
  atomicMax((int*)&X1[(size_t)g * 512 + t], __float_as_int(mx));
  atomicAdd(&X1[(size_t)g * 512 + 256 + t], sm);   // raw sum; /512 in mlp
}

// ---------------------------------------------------------------- agg -------
// Gather segment_sum, batched: per row, 8 cols per broadcast ds_read_b128
// (pipelined one batch ahead); half-waves split the 8 edges; 4 feats/lane.
__global__ __launch_bounds__(512) void agg_gather_kernel(const u16* __restrict__ H,
                                                         const u16* __restrict__ csr_col,
                                                         const u32* __restrict__ csr_off,
                                                         u16* __restrict__ AGG) {
  __shared__ __align__(16) u16 hs[513 * AS];        // 135,432 B (row 512 = zeros)
  __shared__ __align__(16) u16 cols[CSR_STRIDE];    // 24,576 B
  __shared__ u32 offs[513];                         // 2,052 B
  const int c = blockIdx.x;          // feature chunk (128 feats)
  const int g = blockIdx.y;
  const int base = g * N_NODES;
  const int t = threadIdx.x;         // 512 threads

  #pragma unroll
  for (int p = 0; p < 32; ++p) {
    const int flat = p * 512 + t;
    const int row = flat >> 5, q = flat & 31;
    *(uint2*)&hs[row * AS + q * 4] =
        *(const uint2*)&H[(size_t)(base + row) * D_DIM + c * 128 + q * 4];
  }
  if (t < 33) *(uint2*)&hs[512 * AS + t * 4] = uint2{0u, 0u};
  #pragma unroll
  for (int p = 0; p < 12; ++p)
    ((u32*)cols)[p * 512 + t] = ((const u32*)(csr_col + (size_t)g * CSR_STRIDE))[p * 512 + t];
  for (int i = t; i < 513; i += 512) offs[i] = csr_off[(size_t)g * 513 + i];
  __syncthreads();

  const int w = t >> 6, lane = t & 63;
  const int h2 = lane >> 5, fl = lane & 31;
  const int i0 = w * 64;
  for (int i = i0; i < i0 + 64; ++i) {
    const u32 s0 = offs[i];
    const int nb = (int)((offs[i + 1] - s0) >> 3);
    float a0 = 0.f, a1 = 0.f, a2 = 0.f, a3 = 0.f;
    if (nb > 0) {
      uint4 cw = *(const uint4*)&cols[s0];
      for (int b = 0; b < nb; ++b) {
        uint4 cwn = cw;
        if (b + 1 < nb) cwn = *(const uint4*)&cols[s0 + (u32)(b + 1) * 8];
        const u32 w01 = h2 ? cw.z : cw.x;
        const u32 w23 = h2 ? cw.w : cw.y;
        const int c0 = w01 & 0xffffu, c1 = w01 >> 16;
        const int c2 = w23 & 0xffffu, c3 = w23 >> 16;
        const uint2 d0 = *(const uint2*)&hs[c0 * AS + fl * 4];
        const uint2 d1 = *(const uint2*)&hs[c1 * AS + fl * 4];
        const uint2 d2 = *(const uint2*)&hs[c2 * AS + fl * 4];
        const uint2 d3 = *(const uint2*)&hs[c3 * AS + fl * 4];
        a0 += u2f(d0.x << 16); a1 += u2f(d0.x & 0xffff0000u);
        a2 += u2f(d0.y << 16); a3 += u2f(d0.y & 0xffff0000u);
        a0 += u2f(d1.x << 16); a1 += u2f(d1.x & 0xffff0000u);
        a2 += u2f(d1.y << 16); a3 += u2f(d1.y & 0xffff0000u);
        a0 += u2f(d2.x << 16); a1 += u2f(d2.x & 0xffff0000u);
        a2 += u2f(d2.y << 16); a3 += u2f(d2.y & 0xffff0000u);
        a0 += u2f(d3.x << 16); a1 += u2f(d3.x & 0xffff0000u);
        a2 += u2f(d3.y << 16); a3 += u2f(d3.y & 0xffff0000u);
        cw = cwn;
      }
    }
    a0 += __shfl_xor(a0, 32); a1 += __shfl_xor(a1, 32);
    a2 += __shfl_xor(a2, 32); a3 += __shfl_xor(a3, 32);
    if (h2 == 0) {
      uint2 o;
      o.x = (u32)f2bf(a0) | ((u32)f2bf(a1) << 16);
      o.y = (u32)f2bf(a2) | ((u32)f2bf(a3) << 16);
      *(uint2*)&AGG[(size_t)(base + i) * D_DIM + c * 128 + fl * 4] = o;
    }
  }
}

// ---------------------------------------------------------------- gemm ------
// Hout = relu(Amat @ Wr + Hmat @ Ws + bias), m97-style async staging:
// global_load_lds width 16, linear LDS dest, inverse-swizzled global source.
__global__ __launch_bounds__(256) void gemm_kernel(const u16* __restrict__ Amat,
                                                   const u16* __restrict__ Hmat,
                                                   const u16* __restrict__ WrT,
                                                   const u16* __restrict__ WsT,
                                                   const float* __restrict__ bias,
                                                   u16* __restrict__ Hout,
                                                   float* __restrict__ x2pool,
                                                   float* __restrict__ score,
                                                   const float* __restrict__ pvec) {
  __shared__ __align__(16) u16 At[128 * 32];
  __shared__ __align__(16) u16 Bt[128 * 32];
  const int m0 = blockIdx.x * 128;
  const int n0 = blockIdx.y * 128;
  const int t = threadIdx.x;
  const int wid = t >> 6, lane = t & 63;
  const int wm = wid >> 1, wn = wid & 1;
  const int r16 = lane & 15, q0 = lane >> 4;

  f32x4 acc[4][4];
  const f32x4 zero = {0.f, 0.f, 0.f, 0.f};
  #pragma unroll
  for (int i = 0; i < 4; ++i)
    #pragma unroll
    for (int jj = 0; jj < 4; ++jj) acc[i][jj] = zero;

  // staging geometry: 16 chunks of 1KB; wave stages chunks wid*4..+3.
  // chunk ch8 covers rows ch8*16..+15 of a [128][32] tile; lane l -> row
  // ch8*16 + (l>>2), LDS qslot l&3, global q = qslot ^ ((row>>1)&3).
  const int srow_off = lane >> 2;
  const int sq = lane & 3;

  #pragma unroll 1
  for (int s = 0; s < 16; ++s) {
    const int ph = s >> 3;
    const int kk = (s & 7) * 32;
    const u16* Ain = ph ? Hmat : Amat;
    const u16* Win = ph ? WsT : WrT;
    #pragma unroll
    for (int j = 0; j < 4; ++j) {
      const int chk = wid * 4 + j;
      const int ch8 = chk & 7;
      const int r = ch8 * 16 + srow_off;
      const int qsrc = sq ^ ((r >> 1) & 3);
      if (chk < 8)
        async_copy16(&Ain[(size_t)(m0 + r) * 256 + kk + qsrc * 8], &At[ch8 * 512]);
      else
        async_copy16(&Win[(size_t)(n0 + r) * 256 + kk + qsrc * 8], &Bt[ch8 * 512]);
    }
    asm volatile("s_waitcnt vmcnt(0)" ::: "memory");
    __syncthreads();
    bf16x8 aF[4], bF[4];
    #pragma unroll
    for (int mi = 0; mi < 4; ++mi) {
      const int arow = wm * 64 + mi * 16 + r16;
      const int qs = q0 ^ ((arow >> 1) & 3);
      aF[mi] = *(const bf16x8*)&At[arow * 32 + qs * 8];
    }
    #pragma unroll
    for (int ni = 0; ni < 4; ++ni) {
      const int brow = wn * 64 + ni * 16 + r16;
      const int qs = q0 ^ ((brow >> 1) & 3);
      bF[ni] = *(const bf16x8*)&Bt[brow * 32 + qs * 8];
    }
    #pragma unroll
    for (int mi = 0; mi < 4; ++mi)
      #pragma unroll
      for (int ni = 0; ni < 4; ++ni)
        acc[mi][ni] = __builtin_amdgcn_mfma_f32_16x16x32_bf16(aF[mi], bF[ni],
                                                              acc[mi][ni], 0, 0, 0);
    __syncthreads();
  }

  const bool do_x2 = (x2pool != nullptr);
  const bool do_sc = (score != nullptr);
  float colmax[4], colsum[4], pv[4], rpart[4][4];
  #pragma unroll
  for (int ni = 0; ni < 4; ++ni) { colmax[ni] = 0.f; colsum[ni] = 0.f; pv[ni] = 0.f; }
  #pragma unroll
  for (int mi = 0; mi < 4; ++mi)
    #pragma unroll
    for (int r = 0; r < 4; ++r) rpart[mi][r] = 0.f;
  if (do_sc) {
    #pragma unroll
    for (int ni = 0; ni < 4; ++ni) pv[ni] = pvec[n0 + wn * 64 + ni * 16 + r16];
  }

  // epilogue: C/D layout col = lane&15, row = (lane>>4)*4 + reg  [m89]
  #pragma unroll
  for (int mi = 0; mi < 4; ++mi) {
    const int growb = m0 + wm * 64 + mi * 16 + q0 * 4;
    #pragma unroll
    for (int ni = 0; ni < 4; ++ni) {
      const int gcol = n0 + wn * 64 + ni * 16 + r16;
      const float bv = bias[gcol];
      #pragma unroll
      for (int r = 0; r < 4; ++r) {
        float v = acc[mi][ni][r] + bv;
        v = fmaxf(v, 0.f);
        Hout[(size_t)(growb + r) * 256 + gcol] = f2bf(v);
        colmax[ni] = fmaxf(colmax[ni], v);
        colsum[ni] += v;
        rpart[mi][r] += v * pv[ni];
      }
    }
  }

  const int gg = m0 >> 9;   // graph index (128-row tile never straddles a graph)
  if (do_x2) {
    #pragma unroll
    for (int ni = 0; ni < 4; ++ni) {
      const int gcol = n0 + wn * 64 + ni * 16 + r16;
      float cm = colmax[ni], cs = colsum[ni];
      cm = fmaxf(cm, __shfl_xor(cm, 16));
      cm = fmaxf(cm, __shfl_xor(cm, 32));
      cs += __shfl_xor(cs, 16);
      cs += __shfl_xor(cs, 32);
      if (q0 == 0) {
        atomicMax((int*)&x2pool[(size_t)gg * 512 + gcol], __float_as_int(cm));
        atomicAdd(&x2pool[(size_t)gg * 512 + 256 + gcol], cs);
      }
    }
  }
  if (do_sc) {
    #pragma unroll
    for (int mi = 0; mi < 4; ++mi) {
      const int growb = m0 + wm * 64 + mi * 16 + q0 * 4;
      #pragma unroll
      for (int r = 0; r < 4; ++r) {
        float sp = rpart[mi][r];
        sp += __shfl_xor(sp, 1);
        sp += __shfl_xor(sp, 2);
        sp += __shfl_xor(sp, 4);
        sp += __shfl_xor(sp, 8);
        if (r16 == 0) atomicAdd(&score[growb + r], sp);
      }
    }
  }
}

// ---------------------------------------------------------------- sort ------
__global__ __launch_bounds__(256) void sort_kernel(const float* __restrict__ score,
                                                   const float* __restrict__ p,
                                                   u16* __restrict__ top_idx,
                                                   float* __restrict__ top_scale) {
  __shared__ float sval[N_NODES];
  __shared__ int sidx[N_NODES];
  __shared__ float wsum[4];
  const int g = blockIdx.x, t = threadIdx.x;

  float pvt = p[t];
  float sq2 = pvt * pvt;
  #pragma unroll
  for (int off = 32; off > 0; off >>= 1) sq2 += __shfl_down(sq2, off);
  if ((t & 63) == 0) wsum[t >> 6] = sq2;
  __syncthreads();
  const float inv_pn = 1.f / (sqrtf(wsum[0] + wsum[1] + wsum[2] + wsum[3]) + 1e-16f);

  for (int n = t; n < N_NODES; n += 256) {
    sval[n] = score[(size_t)g * 512 + n] * inv_pn;
    sidx[n] = n;
  }
  __syncthreads();

  for (int k = 2; k <= N_NODES; k <<= 1) {
    for (int jj = k >> 1; jj > 0; jj >>= 1) {
      const int i = ((t & ~(jj - 1)) << 1) | (t & (jj - 1));
      const int ix = i | jj;
      const bool dirDesc = ((i & k) == 0);
      const float vi = sval[i], vx = sval[ix];
      const int ii = sidx[i], ij = sidx[ix];
      const bool iAfter = (vi < vx) || (vi == vx && ii > ij);
      if (dirDesc ? iAfter : !iAfter) {
        sval[i] = vx; sval[ix] = vi;
        sidx[i] = ij; sidx[ix] = ii;
      }
      __syncthreads();
    }
  }

  for (int s = t; s < K_TOP; s += 256) {
    top_idx[(size_t)g * 416 + s] = (u16)sidx[s];
    top_scale[(size_t)g * 416 + s] = tanhf(sval[s]);
  }
}

// ---------------------------------------------------------------- x3 pool ---
__global__ __launch_bounds__(256) void x3_pool_kernel(const u16* __restrict__ H3,
                                                      const u16* __restrict__ top_idx,
                                                      const float* __restrict__ top_scale,
                                                      float* __restrict__ X3) {
  __shared__ u16 sidxL[416];
  __shared__ float ssclL[416];
  __shared__ float redm[32 * 65];
  __shared__ float reds[32 * 65];
  const int c = blockIdx.x;          // 0..3
  const int g = blockIdx.y;
  const int t = threadIdx.x;
  const int fl = t & 7, rg = t >> 3;

  for (int s = t; s < K_TOP; s += 256) {
    sidxL[s] = top_idx[(size_t)g * 416 + s];
    ssclL[s] = top_scale[(size_t)g * 416 + s];
  }
  __syncthreads();

  float mx[8], sm[8];
  #pragma unroll
  for (int j = 0; j < 8; ++j) { mx[j] = -1e30f; sm[j] = 0.f; }
  const size_t rowbase = (size_t)g * 512;
  for (int s = rg; s < K_TOP; s += 32) {
    const int row = sidxL[s];
    const float sc = ssclL[s];
    const uint4 d = *(const uint4*)&H3[(rowbase + row) * 256 + c * 64 + fl * 8];
    const u32 wv[4] = {d.x, d.y, d.z, d.w};
    #pragma unroll
    for (int q = 0; q < 4; ++q) {
      const float v0 = u2f(wv[q] << 16) * sc;
      const float v1 = u2f(wv[q] & 0xffff0000u) * sc;
      mx[q * 2] = fmaxf(mx[q * 2], v0); sm[q * 2] += v0;
      mx[q * 2 + 1] = fmaxf(mx[q * 2 + 1], v1); sm[q * 2 + 1] += v1;
    }
  }
  #pragma unroll
  for (int j = 0; j < 8; ++j) {
    redm[rg * 65 + fl * 8 + j] = mx[j];
    reds[rg * 65 + fl * 8 + j] = sm[j];
  }
  __syncthreads();
  for (int st = 16; st >= 1; st >>= 1) {
    if (rg < st) {
      #pragma unroll
      for (int j = 0; j < 8; ++j) {
        const int a = rg * 65 + fl * 8 + j, b = (rg + st) * 65 + fl * 8 + j;
        redm[a] = fmaxf(redm[a], redm[b]);
        reds[a] += reds[b];
      }
    }
    __syncthreads();
  }
  if (rg == 0) {
    #pragma unroll
    for (int j = 0; j < 8; ++j) {
      X3[(size_t)g * 512 + c * 64 + fl * 8 + j] = redm[fl * 8 + j];
      X3[(size_t)g * 512 + 256 + c * 64 + fl * 8 + j] = reds[fl * 8 + j] * (1.f / (float)K_TOP);
    }
  }
}

// ---------------------------------------------------------------- mlp -------
__global__ void mlp_kernel(const float* __restrict__ X1, const float* __restrict__ X2,
                           const float* __restrict__ X3,
                           const float* __restrict__ W1, const float* __restrict__ c1,
                           const float* __restrict__ W2, const float* __restrict__ c2,
                           const float* __restrict__ W3, const float* __restrict__ c3,
                           float* __restrict__ out) {
  __shared__ float zs[512];
  __shared__ float z1[256];
  __shared__ float z2[128];
  const int g = blockIdx.x, t = threadIdx.x;
  for (int k = t; k < 512; k += 256) {
    const float x1v = X1[(size_t)g * 512 + k];
    const float x2v = X2[(size_t)g * 512 + k];
    const float x3v = X3[(size_t)g * 512 + k];
    // x1/x2 sum halves are raw sums; mean = /512 here
    zs[k] = (k < 256) ? (x1v + x2v + x3v)
                      : (x1v * (1.f / 512.f) + x2v * (1.f / 512.f) + x3v);
  }
  __syncthreads();
  {
    float acc = c1[t];
    for (int k = 0; k < 512; ++k) acc += zs[k] * W1[(size_t)k * 256 + t];
    z1[t] = fmaxf(acc, 0.f);
  }
  __syncthreads();
  if (t < 128) {
    float acc = c2[t];
    for (int d = 0; d < 256; ++d) acc += z1[d] * W2[(size_t)d * 128 + t];
    z2[t] = fmaxf(acc, 0.f);
  }
  __syncthreads();
  if (t == 0) {
    float acc = c3[0];
    for (int e = 0; e < 128; ++e) acc += z2[e] * W3[e];
    out[g] = 1.f / (1.f + expf(-acc));
  }
}

// ---------------------------------------------------------------- launch ----
extern "C" void kernel_launch(void* const* d_in, const int* in_sizes, int n_in,
                              void* d_out, int out_size, void* d_ws, size_t ws_size,
                              hipStream_t stream) {
  (void)in_sizes; (void)n_in; (void)out_size; (void)ws_size;
  const float* x   = (const float*)d_in[0];
  const int* src   = (const int*)d_in[1];
  const int* dstp  = (const int*)d_in[2];
  const float* Wr1 = (const float*)d_in[3];
  const float* Ws1 = (const float*)d_in[4];
  const float* b1  = (const float*)d_in[5];
  const float* Wr2 = (const float*)d_in[6];
  const float* Ws2 = (const float*)d_in[7];
  const float* b2  = (const float*)d_in[8];
  const float* Wr3 = (const float*)d_in[9];
  const float* Ws3 = (const float*)d_in[10];
  const float* b3  = (const float*)d_in[11];
  const float* pat = (const float*)d_in[12];
  const float* W1  = (const float*)d_in[13];
  const float* c1  = (const float*)d_in[14];
  const float* W2  = (const float*)d_in[15];
  const float* c2  = (const float*)d_in[16];
  const float* W3  = (const float*)d_in[17];
  const float* c3  = (const float*)d_in[18];
  float* out = (float*)d_out;

  char* ws = (char*)d_ws;
  u16* hA  = (u16*)(ws);                 // 32 MB  (h1, later h3)
  u16* hB  = (u16*)(ws + 33554432);      // 32 MB  (h2)
  u16* AGG = (u16*)(ws + 67108864);      // 32 MB
  u16* WT  = (u16*)(ws + 100663296);     // 512 KB
  float* x1 = (float*)(ws + 101187584);  // 256 KB
  float* x2 = (float*)(ws + 101449728);  // 256 KB (contiguous after x1)
  float* x3 = (float*)(ws + 101711872);  // 256 KB
  u16* csr_col = (u16*)(ws + 101974016); // 3 MB (padded lists; dead after agg#2)
  u32* csr_off = (u32*)(ws + 105119744); // 263 KB
  // aliases into dead csr_col region (used only after agg#2):
  float* score     = (float*)(ws + 101974016);            // 256 KB
  u16* top_idx     = (u16*)(ws + 101974016 + 262144);     // 104 KB
  float* top_scale = (float*)(ws + 101974016 + 372736);   // 208 KB

  prep_kernel<<<dim3(256, 4), dim3(256), 0, stream>>>(Wr2, Ws2, Wr3, Ws3, WT);
  csr_kernel<<<dim3(128), dim3(256), 0, stream>>>(src, dstp, csr_col, csr_off);
  zero_kernel<<<dim3(128), dim3(256), 0, stream>>>(x1);   // zeros x1 + x2 (contiguous)
  conv1_kernel<<<dim3(2, 128), dim3(256), 0, stream>>>(x, csr_col, csr_off, Wr1, Ws1, b1, hA, x1);

  agg_gather_kernel<<<dim3(2, 128), dim3(512), 0, stream>>>(hA, csr_col, csr_off, AGG);
  gemm_kernel<<<dim3(512, 2), dim3(256), 0, stream>>>(AGG, hA, WT, WT + 65536, b2, hB,
                                                      x2, nullptr, nullptr);

  agg_gather_kernel<<<dim3(2, 128), dim3(512), 0, stream>>>(hB, csr_col, csr_off, AGG);
  zero_kernel<<<dim3(64), dim3(256), 0, stream>>>(score);
  gemm_kernel<<<dim3(512, 2), dim3(256), 0, stream>>>(AGG, hB, WT + 131072, WT + 196608, b3, hA,
                                                      nullptr, score, pat);

  sort_kernel<<<dim3(128), dim3(256), 0, stream>>>(score, pat, top_idx, top_scale);
  x3_pool_kernel<<<dim3(4, 128), dim3(256), 0, stream>>>(hA, top_idx, top_scale, x3);
  mlp_kernel<<<dim3(128), dim3(256), 0, stream>>>(x1, x2, x3, W1, c1, W2, c2, W3, c3, out);
}

// Round 5
// 267.094 us; speedup vs baseline: 11.5822x; 1.0614x over previous
//
#include <hip/hip_runtime.h>

typedef unsigned short u16;
typedef unsigned int u32;

#define B_GRAPHS 128
#define N_NODES  512
#define D_DIM    256
#define E_EDGES  8192
#define K_TOP    410
#define CSR_STRIDE 12288   // padded per-graph edge-list capacity (8-aligned rows)
#define AS 132             // hs row stride in u16 (8B-aligned for uint2 ops)

typedef __attribute__((ext_vector_type(8))) __bf16 bf16x8;
typedef __attribute__((ext_vector_type(4))) float  f32x4;

__device__ __forceinline__ float bf2f(u16 h) {
  union { u32 u; float f; } c; c.u = ((u32)h) << 16; return c.f;
}
__device__ __forceinline__ float u2f(u32 u) {
  union { u32 u; float f; } c; c.u = u; return c.f;
}
__device__ __forceinline__ u16 f2bf(float f) {
  union { float f; u32 u; } c; c.f = f;
  u32 u = c.u;
  u += 0x7fffu + ((u >> 16) & 1u);   // round-to-nearest-even
  return (u16)(u >> 16);
}
__device__ __forceinline__ void async_copy16(const void* g, void* l) {
  __builtin_amdgcn_global_load_lds((const __attribute__((address_space(1))) void*)g,
                                   (__attribute__((address_space(3))) void*)l, 16, 0, 0);
}

// ---------------------------------------------------------------- zero ------
__global__ void zero_kernel(float* __restrict__ p) {
  *(float4*)&p[(size_t)(blockIdx.x * 256 + threadIdx.x) * 4] = float4{0.f, 0.f, 0.f, 0.f};
}

// ---------------------------------------------------------------- prep ------
// WT layout: [mat][n][k] bf16, mat in {Wr2, Ws2, Wr3, Ws3}
__global__ void prep_kernel(const float* __restrict__ Wr2, const float* __restrict__ Ws2,
                            const float* __restrict__ Wr3, const float* __restrict__ Ws3,
                            u16* __restrict__ WT) {
  const int mat = blockIdx.y;
  const int n = blockIdx.x;
  const int k = threadIdx.x;
  const float* W = (mat == 0) ? Wr2 : (mat == 1) ? Ws2 : (mat == 2) ? Wr3 : Ws3;
  WT[((size_t)mat << 16) + ((size_t)n << 8) + k] = f2bf(W[(size_t)k * 256 + n]);
}

// ---------------------------------------------------------------- csr -------
// Per-graph CSR, rows padded to multiples of 8 with dummy col 512 (zero row).
// Parallel Hillis-Steele scan for the offsets.
__global__ __launch_bounds__(256) void csr_kernel(const int* __restrict__ src,
                                                  const int* __restrict__ dst,
                                                  u16* __restrict__ csr_col,
                                                  u32* __restrict__ csr_off) {
  __shared__ u32 cnt[512];
  __shared__ u32 scan[512];
  __shared__ u32 poff[513];
  const int g = blockIdx.x, t = threadIdx.x;
  const int base = g * N_NODES, ebase = g * E_EDGES;
  for (int i = t; i < 512; i += 256) cnt[i] = 0;
  __syncthreads();
  for (int e = t; e < E_EDGES; e += 256)
    atomicAdd(&cnt[dst[ebase + e] - base], 1u);
  __syncthreads();
  // inclusive scan of padded counts (512 elems, 256 threads, 2 per thread)
  for (int i = t; i < 512; i += 256) scan[i] = (cnt[i] + 7u) & ~7u;
  __syncthreads();
  #pragma unroll 1
  for (int d = 1; d < 512; d <<= 1) {
    const u32 v0 = (t >= d) ? scan[t - d] : 0u;
    const u32 v1 = scan[t + 256 - d];
    __syncthreads();
    if (t >= d) scan[t] += v0;
    scan[t + 256] += v1;
    __syncthreads();
  }
  if (t == 0) poff[0] = 0;
  for (int i = t; i < 512; i += 256) poff[i + 1] = scan[i];
  __syncthreads();
  for (int i = t; i < 513; i += 256) csr_off[(size_t)g * 513 + i] = poff[i];
  // fill pad slots with the zero-row col
  for (int i = t; i < 512; i += 256) {
    const u32 s = poff[i] + cnt[i], e2 = poff[i + 1];
    for (u32 k = s; k < e2; ++k) csr_col[(size_t)g * CSR_STRIDE + k] = 512;
  }
  __syncthreads();
  for (int i = t; i < 512; i += 256) cnt[i] = poff[i];
  __syncthreads();
  for (int e = t; e < E_EDGES; e += 256) {
    const int d = dst[ebase + e] - base;
    const int s = src[ebase + e] - base;
    const u32 pos = atomicAdd(&cnt[d], 1u);
    csr_col[(size_t)g * CSR_STRIDE + pos] = (u16)s;
  }
}

// ---------------------------------------------------------------- conv1 -----
// Block (c,g): graph g, node half c (256 nodes). Gather duplicated per block
// (batched 8-col reads), matmul+relu+H1 for its node half, x1 pool via atomics.
__global__ __launch_bounds__(256) void conv1_kernel(const float* __restrict__ x,
                             const u16* __restrict__ csr_col, const u32* __restrict__ csr_off,
                             const float* __restrict__ Wr1, const float* __restrict__ Ws1,
                             const float* __restrict__ b1,
                             u16* __restrict__ H1, float* __restrict__ X1) {
  __shared__ float xs[513 * 4];        // +zero row 512
  __shared__ float aggs[N_NODES * 5];
  __shared__ __align__(16) u16 cols[CSR_STRIDE];
  __shared__ u32 offs[513];
  const int c = blockIdx.x;            // node half 0/1
  const int g = blockIdx.y;
  const int base = g * N_NODES;
  const int t = threadIdx.x;           // 256 threads

  for (int i = t; i < N_NODES; i += 256)
    *(float4*)&xs[i * 4] = *(const float4*)&x[(size_t)(base + i) * 4];
  if (t < 4) xs[512 * 4 + t] = 0.f;
  for (int i = t; i < CSR_STRIDE / 2; i += 256)
    ((u32*)cols)[i] = ((const u32*)(csr_col + (size_t)g * CSR_STRIDE))[i];
  for (int i = t; i < 513; i += 256) offs[i] = csr_off[(size_t)g * 513 + i];
  __syncthreads();

  // gather (all 512 rows; 2 per thread), 8-col batches
  #pragma unroll
  for (int nn = 0; nn < 2; ++nn) {
    const int i = t * 2 + nn;
    const u32 s0 = offs[i];
    const int nb = (int)((offs[i + 1] - s0) >> 3);
    float a0 = 0.f, a1 = 0.f, a2 = 0.f, a3 = 0.f;
    for (int b = 0; b < nb; ++b) {
      const uint4 cw = *(const uint4*)&cols[s0 + (u32)b * 8];
      const u32 ww[4] = {cw.x, cw.y, cw.z, cw.w};
      #pragma unroll
      for (int q = 0; q < 4; ++q) {
        const int ca = ww[q] & 0xffffu, cb = ww[q] >> 16;
        const float4 va = *(const float4*)&xs[ca * 4];
        const float4 vb = *(const float4*)&xs[cb * 4];
        a0 += va.x + vb.x; a1 += va.y + vb.y;
        a2 += va.z + vb.z; a3 += va.w + vb.w;
      }
    }
    aggs[i * 5 + 0] = a0; aggs[i * 5 + 1] = a1;
    aggs[i * 5 + 2] = a2; aggs[i * 5 + 3] = a3;
  }
  __syncthreads();

  // matmul over this block's 256 nodes; thread t = output feature
  float wr[4], wsv[4];
  #pragma unroll
  for (int k = 0; k < 4; ++k) { wr[k] = Wr1[k * 256 + t]; wsv[k] = Ws1[k * 256 + t]; }
  const float bb = b1[t];
  float mx = 0.f, sm = 0.f;   // relu => >= 0
  const int nlo = c * 256;
  for (int n = nlo; n < nlo + 256; ++n) {
    float acc = bb;
    #pragma unroll
    for (int k = 0; k < 4; ++k) acc += aggs[n * 5 + k] * wr[k] + xs[n * 4 + k] * wsv[k];
    acc = fmaxf(acc, 0.f);
    H1[(size_t)(base + n) * D_DIM + t] = f2bf(acc);
    mx = fmaxf(mx, acc);
    sm += acc;
  }
  atomicMax((int*)&X1[(size_t)g * 512 + t], __float_as_int(mx));
  atomicAdd(&X1[(size_t)g * 512 + 256 + t], sm);   // raw sum; /512 in mlp
}

// ---------------------------------------------------------------- agg -------
// Gather segment_sum: 4 rows processed concurrently per wave (independent
// LDS dependency chains -> latency hidden). Out-of-range batches redirect to
// a padded zero-col batch (wave-uniform cselect). Half-waves split the 8
// edges of a batch; 4 feats/lane; shfl_xor(32) combine.
__global__ __launch_bounds__(512) void agg_gather_kernel(const u16* __restrict__ H,
                                                         const u16* __restrict__ csr_col,
                                                         const u32* __restrict__ csr_off,
                                                         u16* __restrict__ AGG) {
  __shared__ __align__(16) u16 hs[513 * AS];        // 135,432 B (row 512 = zeros)
  __shared__ __align__(16) u16 cols[CSR_STRIDE + 8];// 24,592 B (+pad batch)
  __shared__ u32 offs[513];                         // 2,052 B
  const int c = blockIdx.x;          // feature chunk (128 feats)
  const int g = blockIdx.y;
  const int base = g * N_NODES;
  const int t = threadIdx.x;         // 512 threads

  #pragma unroll
  for (int p = 0; p < 32; ++p) {
    const int flat = p * 512 + t;
    const int row = flat >> 5, q = flat & 31;
    *(uint2*)&hs[row * AS + q * 4] =
        *(const uint2*)&H[(size_t)(base + row) * D_DIM + c * 128 + q * 4];
  }
  if (t < 33) *(uint2*)&hs[512 * AS + t * 4] = uint2{0u, 0u};
  #pragma unroll
  for (int p = 0; p < 12; ++p)
    ((u32*)cols)[p * 512 + t] = ((const u32*)(csr_col + (size_t)g * CSR_STRIDE))[p * 512 + t];
  if (t < 8) cols[CSR_STRIDE + t] = 512;            // pad batch -> zero row
  for (int i = t; i < 513; i += 512) offs[i] = csr_off[(size_t)g * 513 + i];
  __syncthreads();

  const int w = t >> 6, lane = t & 63;
  const int h2 = lane >> 5, fl = lane & 31;
  const int i0 = w * 64;
  #pragma unroll 1
  for (int j = 0; j < 16; ++j) {
    u32 s0[4]; int nb[4];
    #pragma unroll
    for (int q = 0; q < 4; ++q) {
      const int r = i0 + q * 16 + j;
      s0[q] = offs[r];
      nb[q] = (int)((offs[r + 1] - s0[q]) >> 3);
    }
    const int nbmax = max(max(nb[0], nb[1]), max(nb[2], nb[3]));
    float a[4][4];
    #pragma unroll
    for (int q = 0; q < 4; ++q) { a[q][0] = 0.f; a[q][1] = 0.f; a[q][2] = 0.f; a[q][3] = 0.f; }
    #pragma unroll 1
    for (int b = 0; b < nbmax; ++b) {
      #pragma unroll
      for (int q = 0; q < 4; ++q) {
        const u32 ca = (b < nb[q]) ? (s0[q] + (u32)b * 8u) : (u32)CSR_STRIDE;
        const uint4 cw = *(const uint4*)&cols[ca];
        const u32 w01 = h2 ? cw.z : cw.x;
        const u32 w23 = h2 ? cw.w : cw.y;
        const int c0 = (int)(w01 & 0xffffu), c1 = (int)(w01 >> 16);
        const int c2 = (int)(w23 & 0xffffu), c3 = (int)(w23 >> 16);
        const uint2 d0 = *(const uint2*)&hs[c0 * AS + fl * 4];
        const uint2 d1 = *(const uint2*)&hs[c1 * AS + fl * 4];
        const uint2 d2 = *(const uint2*)&hs[c2 * AS + fl * 4];
        const uint2 d3 = *(const uint2*)&hs[c3 * AS + fl * 4];
        a[q][0] += (u2f(d0.x << 16) + u2f(d1.x << 16)) + (u2f(d2.x << 16) + u2f(d3.x << 16));
        a[q][1] += (u2f(d0.x & 0xffff0000u) + u2f(d1.x & 0xffff0000u))
                 + (u2f(d2.x & 0xffff0000u) + u2f(d3.x & 0xffff0000u));
        a[q][2] += (u2f(d0.y << 16) + u2f(d1.y << 16)) + (u2f(d2.y << 16) + u2f(d3.y << 16));
        a[q][3] += (u2f(d0.y & 0xffff0000u) + u2f(d1.y & 0xffff0000u))
                 + (u2f(d2.y & 0xffff0000u) + u2f(d3.y & 0xffff0000u));
      }
    }
    #pragma unroll
    for (int q = 0; q < 4; ++q) {
      const float r0 = a[q][0] + __shfl_xor(a[q][0], 32);
      const float r1 = a[q][1] + __shfl_xor(a[q][1], 32);
      const float r2 = a[q][2] + __shfl_xor(a[q][2], 32);
      const float r3 = a[q][3] + __shfl_xor(a[q][3], 32);
      if (h2 == 0) {
        uint2 o;
        o.x = (u32)f2bf(r0) | ((u32)f2bf(r1) << 16);
        o.y = (u32)f2bf(r2) | ((u32)f2bf(r3) << 16);
        *(uint2*)&AGG[(size_t)(base + i0 + q * 16 + j) * D_DIM + c * 128 + fl * 4] = o;
      }
    }
  }
}

// ---------------------------------------------------------------- gemm ------
// Hout = relu(Amat @ Wr + Hmat @ Ws + bias). Double-buffered async staging
// (global_load_lds w16), counted vmcnt(4) - never drained mid-loop - and raw
// s_barrier (avoids __syncthreads' implicit vmcnt(0) drain).
__global__ __launch_bounds__(256) void gemm_kernel(const u16* __restrict__ Amat,
                                                   const u16* __restrict__ Hmat,
                                                   const u16* __restrict__ WrT,
                                                   const u16* __restrict__ WsT,
                                                   const float* __restrict__ bias,
                                                   u16* __restrict__ Hout,
                                                   float* __restrict__ x2pool,
                                                   float* __restrict__ score,
                                                   const float* __restrict__ pvec) {
  __shared__ __align__(16) u16 At[2][128 * 32];
  __shared__ __align__(16) u16 Bt[2][128 * 32];
  const int m0 = blockIdx.x * 128;
  const int n0 = blockIdx.y * 128;
  const int t = threadIdx.x;
  const int wid = t >> 6, lane = t & 63;
  const int wm = wid >> 1, wn = wid & 1;
  const int r16 = lane & 15, q0 = lane >> 4;

  f32x4 acc[4][4];
  const f32x4 zero = {0.f, 0.f, 0.f, 0.f};
  #pragma unroll
  for (int i = 0; i < 4; ++i)
    #pragma unroll
    for (int jj = 0; jj < 4; ++jj) acc[i][jj] = zero;

  // staging geometry: 16 chunks of 1KB; wave stages chunks wid*4..+3.
  // chunk ch8 covers rows ch8*16..+15 of a [128][32] tile; lane l -> row
  // ch8*16 + (l>>2), LDS qslot l&3, global q = qslot ^ ((row>>1)&3).
  const int srow_off = lane >> 2;
  const int sq = lane & 3;

  auto stage = [&](int s) {
    const int buf = s & 1;
    const int ph = s >> 3;
    const int kk = (s & 7) * 32;
    const u16* Ain = ph ? Hmat : Amat;
    const u16* Win = ph ? WsT : WrT;
    #pragma unroll
    for (int j = 0; j < 4; ++j) {
      const int chk = wid * 4 + j;
      const int ch8 = chk & 7;
      const int r = ch8 * 16 + srow_off;
      const int qsrc = sq ^ ((r >> 1) & 3);
      if (chk < 8)
        async_copy16(&Ain[(size_t)(m0 + r) * 256 + kk + qsrc * 8], &At[buf][ch8 * 512]);
      else
        async_copy16(&Win[(size_t)(n0 + r) * 256 + kk + qsrc * 8], &Bt[buf][ch8 * 512]);
    }
  };

  stage(0);
  #pragma unroll 1
  for (int s = 0; s < 16; ++s) {
    if (s < 15) {
      stage(s + 1);
      asm volatile("s_waitcnt vmcnt(4)" ::: "memory");
    } else {
      asm volatile("s_waitcnt vmcnt(0)" ::: "memory");
    }
    __builtin_amdgcn_s_barrier();
    const int buf = s & 1;
    bf16x8 aF[4], bF[4];
    #pragma unroll
    for (int mi = 0; mi < 4; ++mi) {
      const int arow = wm * 64 + mi * 16 + r16;
      const int qs = q0 ^ ((arow >> 1) & 3);
      aF[mi] = *(const bf16x8*)&At[buf][arow * 32 + qs * 8];
    }
    #pragma unroll
    for (int ni = 0; ni < 4; ++ni) {
      const int brow = wn * 64 + ni * 16 + r16;
      const int qs = q0 ^ ((brow >> 1) & 3);
      bF[ni] = *(const bf16x8*)&Bt[buf][brow * 32 + qs * 8];
    }
    #pragma unroll
    for (int mi = 0; mi < 4; ++mi)
      #pragma unroll
      for (int ni = 0; ni < 4; ++ni)
        acc[mi][ni] = __builtin_amdgcn_mfma_f32_16x16x32_bf16(aF[mi], bF[ni],
                                                              acc[mi][ni], 0, 0, 0);
    __builtin_amdgcn_s_barrier();
  }

  const bool do_x2 = (x2pool != nullptr);
  const bool do_sc = (score != nullptr);
  float colmax[4], colsum[4], pv[4], rpart[4][4];
  #pragma unroll
  for (int ni = 0; ni < 4; ++ni) { colmax[ni] = 0.f; colsum[ni] = 0.f; pv[ni] = 0.f; }
  #pragma unroll
  for (int mi = 0; mi < 4; ++mi)
    #pragma unroll
    for (int r = 0; r < 4; ++r) rpart[mi][r] = 0.f;
  if (do_sc) {
    #pragma unroll
    for (int ni = 0; ni < 4; ++ni) pv[ni] = pvec[n0 + wn * 64 + ni * 16 + r16];
  }

  // epilogue: C/D layout col = lane&15, row = (lane>>4)*4 + reg  [m89]
  #pragma unroll
  for (int mi = 0; mi < 4; ++mi) {
    const int growb = m0 + wm * 64 + mi * 16 + q0 * 4;
    #pragma unroll
    for (int ni = 0; ni < 4; ++ni) {
      const int gcol = n0 + wn * 64 + ni * 16 + r16;
      const float bv = bias[gcol];
      #pragma unroll
      for (int r = 0; r < 4; ++r) {
        float v = acc[mi][ni][r] + bv;
        v = fmaxf(v, 0.f);
        Hout[(size_t)(growb + r) * 256 + gcol] = f2bf(v);
        colmax[ni] = fmaxf(colmax[ni], v);
        colsum[ni] += v;
        rpart[mi][r] += v * pv[ni];
      }
    }
  }

  const int gg = m0 >> 9;   // graph index (128-row tile never straddles a graph)
  if (do_x2) {
    #pragma unroll
    for (int ni = 0; ni < 4; ++ni) {
      const int gcol = n0 + wn * 64 + ni * 16 + r16;
      float cm = colmax[ni], cs = colsum[ni];
      cm = fmaxf(cm, __shfl_xor(cm, 16));
      cm = fmaxf(cm, __shfl_xor(cm, 32));
      cs += __shfl_xor(cs, 16);
      cs += __shfl_xor(cs, 32);
      if (q0 == 0) {
        atomicMax((int*)&x2pool[(size_t)gg * 512 + gcol], __float_as_int(cm));
        atomicAdd(&x2pool[(size_t)gg * 512 + 256 + gcol], cs);
      }
    }
  }
  if (do_sc) {
    #pragma unroll
    for (int mi = 0; mi < 4; ++mi) {
      const int growb = m0 + wm * 64 + mi * 16 + q0 * 4;
      #pragma unroll
      for (int r = 0; r < 4; ++r) {
        float sp = rpart[mi][r];
        sp += __shfl_xor(sp, 1);
        sp += __shfl_xor(sp, 2);
        sp += __shfl_xor(sp, 4);
        sp += __shfl_xor(sp, 8);
        if (r16 == 0) atomicAdd(&score[growb + r], sp);
      }
    }
  }
}

// ---------------------------------------------------------------- sort ------
__global__ __launch_bounds__(256) void sort_kernel(const float* __restrict__ score,
                                                   const float* __restrict__ p,
                                                   u16* __restrict__ top_idx,
                                                   float* __restrict__ top_scale) {
  __shared__ float sval[N_NODES];
  __shared__ int sidx[N_NODES];
  __shared__ float wsum[4];
  const int g = blockIdx.x, t = threadIdx.x;

  float pvt = p[t];
  float sq2 = pvt * pvt;
  #pragma unroll
  for (int off = 32; off > 0; off >>= 1) sq2 += __shfl_down(sq2, off);
  if ((t & 63) == 0) wsum[t >> 6] = sq2;
  __syncthreads();
  const float inv_pn = 1.f / (sqrtf(wsum[0] + wsum[1] + wsum[2] + wsum[3]) + 1e-16f);

  for (int n = t; n < N_NODES; n += 256) {
    sval[n] = score[(size_t)g * 512 + n] * inv_pn;
    sidx[n] = n;
  }
  __syncthreads();

  for (int k = 2; k <= N_NODES; k <<= 1) {
    for (int jj = k >> 1; jj > 0; jj >>= 1) {
      const int i = ((t & ~(jj - 1)) << 1) | (t & (jj - 1));
      const int ix = i | jj;
      const bool dirDesc = ((i & k) == 0);
      const float vi = sval[i], vx = sval[ix];
      const int ii = sidx[i], ij = sidx[ix];
      const bool iAfter = (vi < vx) || (vi == vx && ii > ij);
      if (dirDesc ? iAfter : !iAfter) {
        sval[i] = vx; sval[ix] = vi;
        sidx[i] = ij; sidx[ix] = ii;
      }
      __syncthreads();
    }
  }

  for (int s = t; s < K_TOP; s += 256) {
    top_idx[(size_t)g * 416 + s] = (u16)sidx[s];
    top_scale[(size_t)g * 416 + s] = tanhf(sval[s]);
  }
}

// ---------------------------------------------------------------- x3 pool ---
__global__ __launch_bounds__(256) void x3_pool_kernel(const u16* __restrict__ H3,
                                                      const u16* __restrict__ top_idx,
                                                      const float* __restrict__ top_scale,
                                                      float* __restrict__ X3) {
  __shared__ u16 sidxL[416];
  __shared__ float ssclL[416];
  __shared__ float redm[32 * 65];
  __shared__ float reds[32 * 65];
  const int c = blockIdx.x;          // 0..3
  const int g = blockIdx.y;
  const int t = threadIdx.x;
  const int fl = t & 7, rg = t >> 3;

  for (int s = t; s < K_TOP; s += 256) {
    sidxL[s] = top_idx[(size_t)g * 416 + s];
    ssclL[s] = top_scale[(size_t)g * 416 + s];
  }
  __syncthreads();

  float mx[8], sm[8];
  #pragma unroll
  for (int j = 0; j < 8; ++j) { mx[j] = -1e30f; sm[j] = 0.f; }
  const size_t rowbase = (size_t)g * 512;
  for (int s = rg; s < K_TOP; s += 32) {
    const int row = sidxL[s];
    const float sc = ssclL[s];
    const uint4 d = *(const uint4*)&H3[(rowbase + row) * 256 + c * 64 + fl * 8];
    const u32 wv[4] = {d.x, d.y, d.z, d.w};
    #pragma unroll
    for (int q = 0; q < 4; ++q) {
      const float v0 = u2f(wv[q] << 16) * sc;
      const float v1 = u2f(wv[q] & 0xffff0000u) * sc;
      mx[q * 2] = fmaxf(mx[q * 2], v0); sm[q * 2] += v0;
      mx[q * 2 + 1] = fmaxf(mx[q * 2 + 1], v1); sm[q * 2 + 1] += v1;
    }
  }
  #pragma unroll
  for (int j = 0; j < 8; ++j) {
    redm[rg * 65 + fl * 8 + j] = mx[j];
    reds[rg * 65 + fl * 8 + j] = sm[j];
  }
  __syncthreads();
  for (int st = 16; st >= 1; st >>= 1) {
    if (rg < st) {
      #pragma unroll
      for (int j = 0; j < 8; ++j) {
        const int a = rg * 65 + fl * 8 + j, b = (rg + st) * 65 + fl * 8 + j;
        redm[a] = fmaxf(redm[a], redm[b]);
        reds[a] += reds[b];
      }
    }
    __syncthreads();
  }
  if (rg == 0) {
    #pragma unroll
    for (int j = 0; j < 8; ++j) {
      X3[(size_t)g * 512 + c * 64 + fl * 8 + j] = redm[fl * 8 + j];
      X3[(size_t)g * 512 + 256 + c * 64 + fl * 8 + j] = reds[fl * 8 + j] * (1.f / (float)K_TOP);
    }
  }
}

// ---------------------------------------------------------------- mlp -------
__global__ void mlp_kernel(const float* __restrict__ X1, const float* __restrict__ X2,
                           const float* __restrict__ X3,
                           const float* __restrict__ W1, const float* __restrict__ c1,
                           const float* __restrict__ W2, const float* __restrict__ c2,
                           const float* __restrict__ W3, const float* __restrict__ c3,
                           float* __restrict__ out) {
  __shared__ float zs[512];
  __shared__ float z1[256];
  __shared__ float z2[128];
  const int g = blockIdx.x, t = threadIdx.x;
  for (int k = t; k < 512; k += 256) {
    const float x1v = X1[(size_t)g * 512 + k];
    const float x2v = X2[(size_t)g * 512 + k];
    const float x3v = X3[(size_t)g * 512 + k];
    // x1/x2 sum halves are raw sums; mean = /512 here
    zs[k] = (k < 256) ? (x1v + x2v + x3v)
                      : (x1v * (1.f / 512.f) + x2v * (1.f / 512.f) + x3v);
  }
  __syncthreads();
  {
    float acc = c1[t];
    for (int k = 0; k < 512; ++k) acc += zs[k] * W1[(size_t)k * 256 + t];
    z1[t] = fmaxf(acc, 0.f);
  }
  __syncthreads();
  if (t < 128) {
    float acc = c2[t];
    for (int d = 0; d < 256; ++d) acc += z1[d] * W2[(size_t)d * 128 + t];
    z2[t] = fmaxf(acc, 0.f);
  }
  __syncthreads();
  if (t == 0) {
    float acc = c3[0];
    for (int e = 0; e < 128; ++e) acc += z2[e] * W3[e];
    out[g] = 1.f / (1.f + expf(-acc));
  }
}

// ---------------------------------------------------------------- launch ----
extern "C" void kernel_launch(void* const* d_in, const int* in_sizes, int n_in,
                              void* d_out, int out_size, void* d_ws, size_t ws_size,
                              hipStream_t stream) {
  (void)in_sizes; (void)n_in; (void)out_size; (void)ws_size;
  const float* x   = (const float*)d_in[0];
  const int* src   = (const int*)d_in[1];
  const int* dstp  = (const int*)d_in[2];
  const float* Wr1 = (const float*)d_in[3];
  const float* Ws1 = (const float*)d_in[4];
  const float* b1  = (const float*)d_in[5];
  const float* Wr2 = (const float*)d_in[6];
  const float* Ws2 = (const float*)d_in[7];
  const float* b2  = (const float*)d_in[8];
  const float* Wr3 = (const float*)d_in[9];
  const float* Ws3 = (const float*)d_in[10];
  const float* b3  = (const float*)d_in[11];
  const float* pat = (const float*)d_in[12];
  const float* W1  = (const float*)d_in[13];
  const float* c1  = (const float*)d_in[14];
  const float* W2  = (const float*)d_in[15];
  const float* c2  = (const float*)d_in[16];
  const float* W3  = (const float*)d_in[17];
  const float* c3  = (const float*)d_in[18];
  float* out = (float*)d_out;

  char* ws = (char*)d_ws;
  u16* hA  = (u16*)(ws);                 // 32 MB  (h1, later h3)
  u16* hB  = (u16*)(ws + 33554432);      // 32 MB  (h2)
  u16* AGG = (u16*)(ws + 67108864);      // 32 MB
  u16* WT  = (u16*)(ws + 100663296);     // 512 KB
  float* x1 = (float*)(ws + 101187584);  // 256 KB
  float* x2 = (float*)(ws + 101449728);  // 256 KB (contiguous after x1)
  float* x3 = (float*)(ws + 101711872);  // 256 KB
  u16* csr_col = (u16*)(ws + 101974016); // 3 MB (padded lists; dead after agg#2)
  u32* csr_off = (u32*)(ws + 105119744); // 263 KB
  // aliases into dead csr_col region (used only after agg#2):
  float* score     = (float*)(ws + 101974016);            // 256 KB
  u16* top_idx     = (u16*)(ws + 101974016 + 262144);     // 104 KB
  float* top_scale = (float*)(ws + 101974016 + 372736);   // 208 KB

  prep_kernel<<<dim3(256, 4), dim3(256), 0, stream>>>(Wr2, Ws2, Wr3, Ws3, WT);
  csr_kernel<<<dim3(128), dim3(256), 0, stream>>>(src, dstp, csr_col, csr_off);
  zero_kernel<<<dim3(128), dim3(256), 0, stream>>>(x1);   // zeros x1 + x2 (contiguous)
  conv1_kernel<<<dim3(2, 128), dim3(256), 0, stream>>>(x, csr_col, csr_off, Wr1, Ws1, b1, hA, x1);

  agg_gather_kernel<<<dim3(2, 128), dim3(512), 0, stream>>>(hA, csr_col, csr_off, AGG);
  gemm_kernel<<<dim3(512, 2), dim3(256), 0, stream>>>(AGG, hA, WT, WT + 65536, b2, hB,
                                                      x2, nullptr, nullptr);

  agg_gather_kernel<<<dim3(2, 128), dim3(512), 0, stream>>>(hB, csr_col, csr_off, AGG);
  zero_kernel<<<dim3(64), dim3(256), 0, stream>>>(score);
  gemm_kernel<<<dim3(512, 2), dim3(256), 0, stream>>>(AGG, hB, WT + 131072, WT + 196608, b3, hA,
                                                      nullptr, score, pat);

  sort_kernel<<<dim3(128), dim3(256), 0, stream>>>(score, pat, top_idx, top_scale);
  x3_pool_kernel<<<dim3(4, 128), dim3(256), 0, stream>>>(hA, top_idx, top_scale, x3);
  mlp_kernel<<<dim3(128), dim3(256), 0, stream>>>(x1, x2, x3, W1, c1, W2, c2, W3, c3, out);
}

// Round 6
// 254.996 us; speedup vs baseline: 12.1317x; 1.0474x over previous
//
#include <hip/hip_runtime.h>

typedef unsigned short u16;
typedef unsigned int u32;

#define B_GRAPHS 128
#define N_NODES  512
#define D_DIM    256
#define E_EDGES  8192
#define K_TOP    410
#define CSR_STRIDE 12288   // global per-graph edge-list capacity (u16, 8-aligned rows)
#define LCOL 11792         // LDS cols: 11776 max padded data + 8 pad batch + align
#define AS 132             // hs row stride in u16 (8B-aligned for uint2 ops)

typedef __attribute__((ext_vector_type(8))) __bf16 bf16x8;
typedef __attribute__((ext_vector_type(4))) float  f32x4;

__device__ __forceinline__ float bf2f(u16 h) {
  union { u32 u; float f; } c; c.u = ((u32)h) << 16; return c.f;
}
__device__ __forceinline__ float u2f(u32 u) {
  union { u32 u; float f; } c; c.u = u; return c.f;
}
__device__ __forceinline__ u16 f2bf(float f) {
  union { float f; u32 u; } c; c.f = f;
  u32 u = c.u;
  u += 0x7fffu + ((u >> 16) & 1u);   // round-to-nearest-even
  return (u16)(u >> 16);
}
__device__ __forceinline__ void async_copy16(const void* g, void* l) {
  __builtin_amdgcn_global_load_lds((const __attribute__((address_space(1))) void*)g,
                                   (__attribute__((address_space(3))) void*)l, 16, 0, 0);
}

// ---------------------------------------------------------------- zero ------
__global__ void zero_kernel(float* __restrict__ p) {
  *(float4*)&p[(size_t)(blockIdx.x * 256 + threadIdx.x) * 4] = float4{0.f, 0.f, 0.f, 0.f};
}

// ---------------------------------------------------------------- prep ------
// WT layout: [mat][n][k] bf16, mat in {Wr2, Ws2, Wr3, Ws3}
__global__ void prep_kernel(const float* __restrict__ Wr2, const float* __restrict__ Ws2,
                            const float* __restrict__ Wr3, const float* __restrict__ Ws3,
                            u16* __restrict__ WT) {
  const int mat = blockIdx.y;
  const int n = blockIdx.x;
  const int k = threadIdx.x;
  const float* W = (mat == 0) ? Wr2 : (mat == 1) ? Ws2 : (mat == 2) ? Wr3 : Ws3;
  WT[((size_t)mat << 16) + ((size_t)n << 8) + k] = f2bf(W[(size_t)k * 256 + n]);
}

// ---------------------------------------------------------------- csr -------
// Per-graph CSR, rows padded to multiples of 8. Cols stored PRE-SCALED by 33
// (LDS row-stride units); pad col = 512*33 = 16896 (zero row).
__global__ __launch_bounds__(256) void csr_kernel(const int* __restrict__ src,
                                                  const int* __restrict__ dst,
                                                  u16* __restrict__ csr_col,
                                                  u32* __restrict__ csr_off) {
  __shared__ u32 cnt[512];
  __shared__ u32 scan[512];
  __shared__ u32 poff[513];
  const int g = blockIdx.x, t = threadIdx.x;
  const int base = g * N_NODES, ebase = g * E_EDGES;
  for (int i = t; i < 512; i += 256) cnt[i] = 0;
  __syncthreads();
  for (int e = t; e < E_EDGES; e += 256)
    atomicAdd(&cnt[dst[ebase + e] - base], 1u);
  __syncthreads();
  for (int i = t; i < 512; i += 256) scan[i] = (cnt[i] + 7u) & ~7u;
  __syncthreads();
  #pragma unroll 1
  for (int d = 1; d < 512; d <<= 1) {
    const u32 v0 = (t >= d) ? scan[t - d] : 0u;
    const u32 v1 = scan[t + 256 - d];
    __syncthreads();
    if (t >= d) scan[t] += v0;
    scan[t + 256] += v1;
    __syncthreads();
  }
  if (t == 0) poff[0] = 0;
  for (int i = t; i < 512; i += 256) poff[i + 1] = scan[i];
  __syncthreads();
  for (int i = t; i < 513; i += 256) csr_off[(size_t)g * 513 + i] = poff[i];
  for (int i = t; i < 512; i += 256) {
    const u32 s = poff[i] + cnt[i], e2 = poff[i + 1];
    for (u32 k = s; k < e2; ++k) csr_col[(size_t)g * CSR_STRIDE + k] = 16896;
  }
  __syncthreads();
  for (int i = t; i < 512; i += 256) cnt[i] = poff[i];
  __syncthreads();
  for (int e = t; e < E_EDGES; e += 256) {
    const int d = dst[ebase + e] - base;
    const int s = src[ebase + e] - base;
    const u32 pos = atomicAdd(&cnt[d], 1u);
    csr_col[(size_t)g * CSR_STRIDE + pos] = (u16)(s * 33);
  }
}

// ---------------------------------------------------------------- conv1 -----
// Block (c,g): graph g, node half c. Cols are c33-scaled -> exact magic-div
// recovers col: col = (c33 * 63551) >> 21  (exact for multiples of 33 < 2^16).
__global__ __launch_bounds__(256) void conv1_kernel(const float* __restrict__ x,
                             const u16* __restrict__ csr_col, const u32* __restrict__ csr_off,
                             const float* __restrict__ Wr1, const float* __restrict__ Ws1,
                             const float* __restrict__ b1,
                             u16* __restrict__ H1, float* __restrict__ X1) {
  __shared__ float xs[513 * 4];        // +zero row 512
  __shared__ float aggs[N_NODES * 5];
  __shared__ __align__(16) u16 cols[CSR_STRIDE];
  __shared__ u32 offs[513];
  const int c = blockIdx.x;            // node half 0/1
  const int g = blockIdx.y;
  const int base = g * N_NODES;
  const int t = threadIdx.x;           // 256 threads

  for (int i = t; i < N_NODES; i += 256)
    *(float4*)&xs[i * 4] = *(const float4*)&x[(size_t)(base + i) * 4];
  if (t < 4) xs[512 * 4 + t] = 0.f;
  for (int i = t; i < CSR_STRIDE / 2; i += 256)
    ((u32*)cols)[i] = ((const u32*)(csr_col + (size_t)g * CSR_STRIDE))[i];
  for (int i = t; i < 513; i += 256) offs[i] = csr_off[(size_t)g * 513 + i];
  __syncthreads();

  #pragma unroll
  for (int nn = 0; nn < 2; ++nn) {
    const int i = t * 2 + nn;
    const u32 s0 = offs[i];
    const int nb = (int)((offs[i + 1] - s0) >> 3);
    float a0 = 0.f, a1 = 0.f, a2 = 0.f, a3 = 0.f;
    for (int b = 0; b < nb; ++b) {
      const uint4 cw = *(const uint4*)&cols[s0 + (u32)b * 8];
      const u32 ww[4] = {cw.x, cw.y, cw.z, cw.w};
      #pragma unroll
      for (int q = 0; q < 4; ++q) {
        const int ca = (int)(((ww[q] & 0xffffu) * 63551u) >> 21);
        const int cb = (int)(((ww[q] >> 16) * 63551u) >> 21);
        const float4 va = *(const float4*)&xs[ca * 4];
        const float4 vb = *(const float4*)&xs[cb * 4];
        a0 += va.x + vb.x; a1 += va.y + vb.y;
        a2 += va.z + vb.z; a3 += va.w + vb.w;
      }
    }
    aggs[i * 5 + 0] = a0; aggs[i * 5 + 1] = a1;
    aggs[i * 5 + 2] = a2; aggs[i * 5 + 3] = a3;
  }
  __syncthreads();

  float wr[4], wsv[4];
  #pragma unroll
  for (int k = 0; k < 4; ++k) { wr[k] = Wr1[k * 256 + t]; wsv[k] = Ws1[k * 256 + t]; }
  const float bb = b1[t];
  float mx = 0.f, sm = 0.f;   // relu => >= 0
  const int nlo = c * 256;
  for (int n = nlo; n < nlo + 256; ++n) {
    float acc = bb;
    #pragma unroll
    for (int k = 0; k < 4; ++k) acc += aggs[n * 5 + k] * wr[k] + xs[n * 4 + k] * wsv[k];
    acc = fmaxf(acc, 0.f);
    H1[(size_t)(base + n) * D_DIM + t] = f2bf(acc);
    mx = fmaxf(mx, acc);
    sm += acc;
  }
  atomicMax((int*)&X1[(size_t)g * 512 + t], __float_as_int(mx));
  atomicAdd(&X1[(size_t)g * 512 + 256 + t], sm);   // raw sum; /512 in mlp
}

// ---------------------------------------------------------------- agg -------
// Gather segment_sum. Per-wave degree sort (in-register bitonic over packed
// (nb<<16)|row keys) groups rows of similar degree -> the 4-row ILP groups
// have ~equal batch counts (max-waste ~3%). Cols pre-scaled by 33; b64 col
// reads at +h2*4 replace b128+select.
__global__ __launch_bounds__(512) void agg_gather_kernel(const u16* __restrict__ H,
                                                         const u16* __restrict__ csr_col,
                                                         const u32* __restrict__ csr_off,
                                                         u16* __restrict__ AGG) {
  __shared__ __align__(16) u16 hs[513 * AS];        // 135,432 B (row 512 = zeros)
  __shared__ __align__(16) u16 cols[LCOL];          // 23,584 B
  __shared__ u32 offs[513];                         // 2,052 B
  __shared__ u32 swork[512];                        // 2,048 B  (total 163,116)
  const int c = blockIdx.x;          // feature chunk (128 feats)
  const int g = blockIdx.y;
  const int base = g * N_NODES;
  const int t = threadIdx.x;         // 512 threads

  #pragma unroll
  for (int p = 0; p < 32; ++p) {
    const int flat = p * 512 + t;
    const int row = flat >> 5, q = flat & 31;
    *(uint2*)&hs[row * AS + q * 4] =
        *(const uint2*)&H[(size_t)(base + row) * D_DIM + c * 128 + q * 4];
  }
  if (t < 33) *(uint2*)&hs[512 * AS + t * 4] = uint2{0u, 0u};
  {
    const u32* colsw = (const u32*)(csr_col + (size_t)g * CSR_STRIDE);
    #pragma unroll
    for (int p = 0; p < 12; ++p) {
      const int i = p * 512 + t;
      if (i < (LCOL - 8) / 2) ((u32*)cols)[i] = colsw[i];
    }
  }
  if (t < 8) cols[LCOL - 8 + t] = 16896;            // pad batch -> zero row
  for (int i = t; i < 513; i += 512) offs[i] = csr_off[(size_t)g * 513 + i];
  __syncthreads();

  const int w = t >> 6, lane = t & 63;
  // per-wave degree sort: key = (nb<<16)|row, bitonic ascending over 64 lanes
  {
    const int row = (w << 6) + lane;
    const u32 s0 = offs[row];
    const u32 nb = (offs[row + 1] - s0) >> 3;
    u32 key = (nb << 16) | (u32)row;
    #pragma unroll
    for (int k = 2; k <= 64; k <<= 1) {
      #pragma unroll
      for (int jj = k >> 1; jj > 0; jj >>= 1) {
        const u32 o = (u32)__shfl_xor((int)key, jj);
        const bool up = ((lane & k) == 0);
        const bool lower = ((lane & jj) == 0);
        const u32 mn = min(key, o), mx = max(key, o);
        key = (up == lower) ? mn : mx;
      }
    }
    swork[(w << 6) + lane] = key;
  }
  __syncthreads();

  const int h2 = lane >> 5, fl = lane & 31;
  const int i0w = w << 6;
  const u32 padu = (u32)(LCOL - 8 + h2 * 4);
  const u32 h2o = (u32)(h2 * 4);
  #pragma unroll 1
  for (int j = 0; j < 16; ++j) {
    const uint4 kw = *(const uint4*)&swork[i0w + j * 4];
    const int r0 = (int)(kw.x & 0xffffu), r1 = (int)(kw.y & 0xffffu);
    const int r2 = (int)(kw.z & 0xffffu), r3 = (int)(kw.w & 0xffffu);
    const int n0b = (int)(kw.x >> 16), n1b = (int)(kw.y >> 16);
    const int n2b = (int)(kw.z >> 16), n3b = (int)(kw.w >> 16);
    const int nbmax = n3b;             // sorted ascending -> slot 3 is max
    u32 cu0 = offs[r0] + h2o, cu1 = offs[r1] + h2o;
    u32 cu2 = offs[r2] + h2o, cu3 = offs[r3] + h2o;
    float a[4][4];
    #pragma unroll
    for (int q = 0; q < 4; ++q) { a[q][0] = 0.f; a[q][1] = 0.f; a[q][2] = 0.f; a[q][3] = 0.f; }
    #pragma unroll 1
    for (int b = 0; b < nbmax; ++b) {
      const u32 u0 = (b < n0b) ? cu0 : padu;
      const u32 u1 = (b < n1b) ? cu1 : padu;
      const u32 u2 = (b < n2b) ? cu2 : padu;
      const u32 u3 = (b < n3b) ? cu3 : padu;
      const u32 uu[4] = {u0, u1, u2, u3};
      #pragma unroll
      for (int q = 0; q < 4; ++q) {
        const uint2 cw = *(const uint2*)&cols[uu[q]];
        const int e0 = (int)(cw.x & 0xffffu), e1 = (int)(cw.x >> 16);
        const int e2 = (int)(cw.y & 0xffffu), e3 = (int)(cw.y >> 16);
        const uint2 d0 = *(const uint2*)&hs[(u32)(e0 + fl) << 2];
        const uint2 d1 = *(const uint2*)&hs[(u32)(e1 + fl) << 2];
        const uint2 d2 = *(const uint2*)&hs[(u32)(e2 + fl) << 2];
        const uint2 d3 = *(const uint2*)&hs[(u32)(e3 + fl) << 2];
        a[q][0] += (u2f(d0.x << 16) + u2f(d1.x << 16)) + (u2f(d2.x << 16) + u2f(d3.x << 16));
        a[q][1] += (u2f(d0.x & 0xffff0000u) + u2f(d1.x & 0xffff0000u))
                 + (u2f(d2.x & 0xffff0000u) + u2f(d3.x & 0xffff0000u));
        a[q][2] += (u2f(d0.y << 16) + u2f(d1.y << 16)) + (u2f(d2.y << 16) + u2f(d3.y << 16));
        a[q][3] += (u2f(d0.y & 0xffff0000u) + u2f(d1.y & 0xffff0000u))
                 + (u2f(d2.y & 0xffff0000u) + u2f(d3.y & 0xffff0000u));
      }
      cu0 += 8; cu1 += 8; cu2 += 8; cu3 += 8;
    }
    const int rw[4] = {r0, r1, r2, r3};
    #pragma unroll
    for (int q = 0; q < 4; ++q) {
      const float v0 = a[q][0] + __shfl_xor(a[q][0], 32);
      const float v1 = a[q][1] + __shfl_xor(a[q][1], 32);
      const float v2 = a[q][2] + __shfl_xor(a[q][2], 32);
      const float v3 = a[q][3] + __shfl_xor(a[q][3], 32);
      if (h2 == 0) {
        uint2 o;
        o.x = (u32)f2bf(v0) | ((u32)f2bf(v1) << 16);
        o.y = (u32)f2bf(v2) | ((u32)f2bf(v3) << 16);
        *(uint2*)&AGG[(size_t)(base + rw[q]) * D_DIM + c * 128 + fl * 4] = o;
      }
    }
  }
}

// ---------------------------------------------------------------- gemm ------
// Hout = relu(Amat @ Wr + Hmat @ Ws + bias). Double-buffered async staging
// (global_load_lds w16), counted vmcnt(4), raw s_barrier.
__global__ __launch_bounds__(256) void gemm_kernel(const u16* __restrict__ Amat,
                                                   const u16* __restrict__ Hmat,
                                                   const u16* __restrict__ WrT,
                                                   const u16* __restrict__ WsT,
                                                   const float* __restrict__ bias,
                                                   u16* __restrict__ Hout,
                                                   float* __restrict__ x2pool,
                                                   float* __restrict__ score,
                                                   const float* __restrict__ pvec) {
  __shared__ __align__(16) u16 At[2][128 * 32];
  __shared__ __align__(16) u16 Bt[2][128 * 32];
  const int m0 = blockIdx.x * 128;
  const int n0 = blockIdx.y * 128;
  const int t = threadIdx.x;
  const int wid = t >> 6, lane = t & 63;
  const int wm = wid >> 1, wn = wid & 1;
  const int r16 = lane & 15, q0 = lane >> 4;

  f32x4 acc[4][4];
  const f32x4 zero = {0.f, 0.f, 0.f, 0.f};
  #pragma unroll
  for (int i = 0; i < 4; ++i)
    #pragma unroll
    for (int jj = 0; jj < 4; ++jj) acc[i][jj] = zero;

  const int srow_off = lane >> 2;
  const int sq = lane & 3;

  auto stage = [&](int s) {
    const int buf = s & 1;
    const int ph = s >> 3;
    const int kk = (s & 7) * 32;
    const u16* Ain = ph ? Hmat : Amat;
    const u16* Win = ph ? WsT : WrT;
    #pragma unroll
    for (int j = 0; j < 4; ++j) {
      const int chk = wid * 4 + j;
      const int ch8 = chk & 7;
      const int r = ch8 * 16 + srow_off;
      const int qsrc = sq ^ ((r >> 1) & 3);
      if (chk < 8)
        async_copy16(&Ain[(size_t)(m0 + r) * 256 + kk + qsrc * 8], &At[buf][ch8 * 512]);
      else
        async_copy16(&Win[(size_t)(n0 + r) * 256 + kk + qsrc * 8], &Bt[buf][ch8 * 512]);
    }
  };

  stage(0);
  #pragma unroll 1
  for (int s = 0; s < 16; ++s) {
    if (s < 15) {
      stage(s + 1);
      asm volatile("s_waitcnt vmcnt(4)" ::: "memory");
    } else {
      asm volatile("s_waitcnt vmcnt(0)" ::: "memory");
    }
    __builtin_amdgcn_s_barrier();
    const int buf = s & 1;
    bf16x8 aF[4], bF[4];
    #pragma unroll
    for (int mi = 0; mi < 4; ++mi) {
      const int arow = wm * 64 + mi * 16 + r16;
      const int qs = q0 ^ ((arow >> 1) & 3);
      aF[mi] = *(const bf16x8*)&At[buf][arow * 32 + qs * 8];
    }
    #pragma unroll
    for (int ni = 0; ni < 4; ++ni) {
      const int brow = wn * 64 + ni * 16 + r16;
      const int qs = q0 ^ ((brow >> 1) & 3);
      bF[ni] = *(const bf16x8*)&Bt[buf][brow * 32 + qs * 8];
    }
    #pragma unroll
    for (int mi = 0; mi < 4; ++mi)
      #pragma unroll
      for (int ni = 0; ni < 4; ++ni)
        acc[mi][ni] = __builtin_amdgcn_mfma_f32_16x16x32_bf16(aF[mi], bF[ni],
                                                              acc[mi][ni], 0, 0, 0);
    __builtin_amdgcn_s_barrier();
  }

  const bool do_x2 = (x2pool != nullptr);
  const bool do_sc = (score != nullptr);
  float colmax[4], colsum[4], pv[4], rpart[4][4];
  #pragma unroll
  for (int ni = 0; ni < 4; ++ni) { colmax[ni] = 0.f; colsum[ni] = 0.f; pv[ni] = 0.f; }
  #pragma unroll
  for (int mi = 0; mi < 4; ++mi)
    #pragma unroll
    for (int r = 0; r < 4; ++r) rpart[mi][r] = 0.f;
  if (do_sc) {
    #pragma unroll
    for (int ni = 0; ni < 4; ++ni) pv[ni] = pvec[n0 + wn * 64 + ni * 16 + r16];
  }

  // epilogue: C/D layout col = lane&15, row = (lane>>4)*4 + reg  [m89]
  #pragma unroll
  for (int mi = 0; mi < 4; ++mi) {
    const int growb = m0 + wm * 64 + mi * 16 + q0 * 4;
    #pragma unroll
    for (int ni = 0; ni < 4; ++ni) {
      const int gcol = n0 + wn * 64 + ni * 16 + r16;
      const float bv = bias[gcol];
      #pragma unroll
      for (int r = 0; r < 4; ++r) {
        float v = acc[mi][ni][r] + bv;
        v = fmaxf(v, 0.f);
        Hout[(size_t)(growb + r) * 256 + gcol] = f2bf(v);
        colmax[ni] = fmaxf(colmax[ni], v);
        colsum[ni] += v;
        rpart[mi][r] += v * pv[ni];
      }
    }
  }

  const int gg = m0 >> 9;   // graph index (128-row tile never straddles a graph)
  if (do_x2) {
    #pragma unroll
    for (int ni = 0; ni < 4; ++ni) {
      const int gcol = n0 + wn * 64 + ni * 16 + r16;
      float cm = colmax[ni], cs = colsum[ni];
      cm = fmaxf(cm, __shfl_xor(cm, 16));
      cm = fmaxf(cm, __shfl_xor(cm, 32));
      cs += __shfl_xor(cs, 16);
      cs += __shfl_xor(cs, 32);
      if (q0 == 0) {
        atomicMax((int*)&x2pool[(size_t)gg * 512 + gcol], __float_as_int(cm));
        atomicAdd(&x2pool[(size_t)gg * 512 + 256 + gcol], cs);
      }
    }
  }
  if (do_sc) {
    #pragma unroll
    for (int mi = 0; mi < 4; ++mi) {
      const int growb = m0 + wm * 64 + mi * 16 + q0 * 4;
      #pragma unroll
      for (int r = 0; r < 4; ++r) {
        float sp = rpart[mi][r];
        sp += __shfl_xor(sp, 1);
        sp += __shfl_xor(sp, 2);
        sp += __shfl_xor(sp, 4);
        sp += __shfl_xor(sp, 8);
        if (r16 == 0) atomicAdd(&score[growb + r], sp);
      }
    }
  }
}

// ---------------------------------------------------------------- sort ------
__global__ __launch_bounds__(256) void sort_kernel(const float* __restrict__ score,
                                                   const float* __restrict__ p,
                                                   u16* __restrict__ top_idx,
                                                   float* __restrict__ top_scale) {
  __shared__ float sval[N_NODES];
  __shared__ int sidx[N_NODES];
  __shared__ float wsum[4];
  const int g = blockIdx.x, t = threadIdx.x;

  float pvt = p[t];
  float sq2 = pvt * pvt;
  #pragma unroll
  for (int off = 32; off > 0; off >>= 1) sq2 += __shfl_down(sq2, off);
  if ((t & 63) == 0) wsum[t >> 6] = sq2;
  __syncthreads();
  const float inv_pn = 1.f / (sqrtf(wsum[0] + wsum[1] + wsum[2] + wsum[3]) + 1e-16f);

  for (int n = t; n < N_NODES; n += 256) {
    sval[n] = score[(size_t)g * 512 + n] * inv_pn;
    sidx[n] = n;
  }
  __syncthreads();

  for (int k = 2; k <= N_NODES; k <<= 1) {
    for (int jj = k >> 1; jj > 0; jj >>= 1) {
      const int i = ((t & ~(jj - 1)) << 1) | (t & (jj - 1));
      const int ix = i | jj;
      const bool dirDesc = ((i & k) == 0);
      const float vi = sval[i], vx = sval[ix];
      const int ii = sidx[i], ij = sidx[ix];
      const bool iAfter = (vi < vx) || (vi == vx && ii > ij);
      if (dirDesc ? iAfter : !iAfter) {
        sval[i] = vx; sval[ix] = vi;
        sidx[i] = ij; sidx[ix] = ii;
      }
      __syncthreads();
    }
  }

  for (int s = t; s < K_TOP; s += 256) {
    top_idx[(size_t)g * 416 + s] = (u16)sidx[s];
    top_scale[(size_t)g * 416 + s] = tanhf(sval[s]);
  }
}

// ---------------------------------------------------------------- x3 pool ---
__global__ __launch_bounds__(256) void x3_pool_kernel(const u16* __restrict__ H3,
                                                      const u16* __restrict__ top_idx,
                                                      const float* __restrict__ top_scale,
                                                      float* __restrict__ X3) {
  __shared__ u16 sidxL[416];
  __shared__ float ssclL[416];
  __shared__ float redm[32 * 65];
  __shared__ float reds[32 * 65];
  const int c = blockIdx.x;          // 0..3
  const int g = blockIdx.y;
  const int t = threadIdx.x;
  const int fl = t & 7, rg = t >> 3;

  for (int s = t; s < K_TOP; s += 256) {
    sidxL[s] = top_idx[(size_t)g * 416 + s];
    ssclL[s] = top_scale[(size_t)g * 416 + s];
  }
  __syncthreads();

  float mx[8], sm[8];
  #pragma unroll
  for (int j = 0; j < 8; ++j) { mx[j] = -1e30f; sm[j] = 0.f; }
  const size_t rowbase = (size_t)g * 512;
  for (int s = rg; s < K_TOP; s += 32) {
    const int row = sidxL[s];
    const float sc = ssclL[s];
    const uint4 d = *(const uint4*)&H3[(rowbase + row) * 256 + c * 64 + fl * 8];
    const u32 wv[4] = {d.x, d.y, d.z, d.w};
    #pragma unroll
    for (int q = 0; q < 4; ++q) {
      const float v0 = u2f(wv[q] << 16) * sc;
      const float v1 = u2f(wv[q] & 0xffff0000u) * sc;
      mx[q * 2] = fmaxf(mx[q * 2], v0); sm[q * 2] += v0;
      mx[q * 2 + 1] = fmaxf(mx[q * 2 + 1], v1); sm[q * 2 + 1] += v1;
    }
  }
  #pragma unroll
  for (int j = 0; j < 8; ++j) {
    redm[rg * 65 + fl * 8 + j] = mx[j];
    reds[rg * 65 + fl * 8 + j] = sm[j];
  }
  __syncthreads();
  for (int st = 16; st >= 1; st >>= 1) {
    if (rg < st) {
      #pragma unroll
      for (int j = 0; j < 8; ++j) {
        const int a = rg * 65 + fl * 8 + j, b = (rg + st) * 65 + fl * 8 + j;
        redm[a] = fmaxf(redm[a], redm[b]);
        reds[a] += reds[b];
      }
    }
    __syncthreads();
  }
  if (rg == 0) {
    #pragma unroll
    for (int j = 0; j < 8; ++j) {
      X3[(size_t)g * 512 + c * 64 + fl * 8 + j] = redm[fl * 8 + j];
      X3[(size_t)g * 512 + 256 + c * 64 + fl * 8 + j] = reds[fl * 8 + j] * (1.f / (float)K_TOP);
    }
  }
}

// ---------------------------------------------------------------- mlp -------
__global__ void mlp_kernel(const float* __restrict__ X1, const float* __restrict__ X2,
                           const float* __restrict__ X3,
                           const float* __restrict__ W1, const float* __restrict__ c1,
                           const float* __restrict__ W2, const float* __restrict__ c2,
                           const float* __restrict__ W3, const float* __restrict__ c3,
                           float* __restrict__ out) {
  __shared__ float zs[512];
  __shared__ float z1[256];
  __shared__ float z2[128];
  const int g = blockIdx.x, t = threadIdx.x;
  for (int k = t; k < 512; k += 256) {
    const float x1v = X1[(size_t)g * 512 + k];
    const float x2v = X2[(size_t)g * 512 + k];
    const float x3v = X3[(size_t)g * 512 + k];
    zs[k] = (k < 256) ? (x1v + x2v + x3v)
                      : (x1v * (1.f / 512.f) + x2v * (1.f / 512.f) + x3v);
  }
  __syncthreads();
  {
    float acc = c1[t];
    for (int k = 0; k < 512; ++k) acc += zs[k] * W1[(size_t)k * 256 + t];
    z1[t] = fmaxf(acc, 0.f);
  }
  __syncthreads();
  if (t < 128) {
    float acc = c2[t];
    for (int d = 0; d < 256; ++d) acc += z1[d] * W2[(size_t)d * 128 + t];
    z2[t] = fmaxf(acc, 0.f);
  }
  __syncthreads();
  if (t == 0) {
    float acc = c3[0];
    for (int e = 0; e < 128; ++e) acc += z2[e] * W3[e];
    out[g] = 1.f / (1.f + expf(-acc));
  }
}

// ---------------------------------------------------------------- launch ----
extern "C" void kernel_launch(void* const* d_in, const int* in_sizes, int n_in,
                              void* d_out, int out_size, void* d_ws, size_t ws_size,
                              hipStream_t stream) {
  (void)in_sizes; (void)n_in; (void)out_size; (void)ws_size;
  const float* x   = (const float*)d_in[0];
  const int* src   = (const int*)d_in[1];
  const int* dstp  = (const int*)d_in[2];
  const float* Wr1 = (const float*)d_in[3];
  const float* Ws1 = (const float*)d_in[4];
  const float* b1  = (const float*)d_in[5];
  const float* Wr2 = (const float*)d_in[6];
  const float* Ws2 = (const float*)d_in[7];
  const float* b2  = (const float*)d_in[8];
  const float* Wr3 = (const float*)d_in[9];
  const float* Ws3 = (const float*)d_in[10];
  const float* b3  = (const float*)d_in[11];
  const float* pat = (const float*)d_in[12];
  const float* W1  = (const float*)d_in[13];
  const float* c1  = (const float*)d_in[14];
  const float* W2  = (const float*)d_in[15];
  const float* c2  = (const float*)d_in[16];
  const float* W3  = (const float*)d_in[17];
  const float* c3  = (const float*)d_in[18];
  float* out = (float*)d_out;

  char* ws = (char*)d_ws;
  u16* hA  = (u16*)(ws);                 // 32 MB  (h1, later h3)
  u16* hB  = (u16*)(ws + 33554432);      // 32 MB  (h2)
  u16* AGG = (u16*)(ws + 67108864);      // 32 MB
  u16* WT  = (u16*)(ws + 100663296);     // 512 KB
  float* x1 = (float*)(ws + 101187584);  // 256 KB
  float* x2 = (float*)(ws + 101449728);  // 256 KB (contiguous after x1)
  float* x3 = (float*)(ws + 101711872);  // 256 KB
  u16* csr_col = (u16*)(ws + 101974016); // 3 MB (c33-scaled; dead after agg#2)
  u32* csr_off = (u32*)(ws + 105119744); // 263 KB
  // aliases into dead csr_col region (used only after agg#2):
  float* score     = (float*)(ws + 101974016);            // 256 KB
  u16* top_idx     = (u16*)(ws + 101974016 + 262144);     // 104 KB
  float* top_scale = (float*)(ws + 101974016 + 372736);   // 208 KB

  prep_kernel<<<dim3(256, 4), dim3(256), 0, stream>>>(Wr2, Ws2, Wr3, Ws3, WT);
  csr_kernel<<<dim3(128), dim3(256), 0, stream>>>(src, dstp, csr_col, csr_off);
  zero_kernel<<<dim3(128), dim3(256), 0, stream>>>(x1);   // zeros x1 + x2 (contiguous)
  conv1_kernel<<<dim3(2, 128), dim3(256), 0, stream>>>(x, csr_col, csr_off, Wr1, Ws1, b1, hA, x1);

  agg_gather_kernel<<<dim3(2, 128), dim3(512), 0, stream>>>(hA, csr_col, csr_off, AGG);
  gemm_kernel<<<dim3(512, 2), dim3(256), 0, stream>>>(AGG, hA, WT, WT + 65536, b2, hB,
                                                      x2, nullptr, nullptr);

  agg_gather_kernel<<<dim3(2, 128), dim3(512), 0, stream>>>(hB, csr_col, csr_off, AGG);
  zero_kernel<<<dim3(64), dim3(256), 0, stream>>>(score);
  gemm_kernel<<<dim3(512, 2), dim3(256), 0, stream>>>(AGG, hB, WT + 131072, WT + 196608, b3, hA,
                                                      nullptr, score, pat);

  sort_kernel<<<dim3(128), dim3(256), 0, stream>>>(score, pat, top_idx, top_scale);
  x3_pool_kernel<<<dim3(4, 128), dim3(256), 0, stream>>>(hA, top_idx, top_scale, x3);
  mlp_kernel<<<dim3(128), dim3(256), 0, stream>>>(x1, x2, x3, W1, c1, W2, c2, W3, c3, out);
}

// Round 7
// 252.828 us; speedup vs baseline: 12.2358x; 1.0086x over previous
//
#include <hip/hip_runtime.h>

typedef unsigned short u16;
typedef unsigned int u32;

#define B_GRAPHS 128
#define N_NODES  512
#define D_DIM    256
#define E_EDGES  8192
#define K_TOP    410
#define CSR_STRIDE 12288   // global per-graph edge-list capacity (u16, 8-aligned rows)

typedef __attribute__((ext_vector_type(8))) __bf16 bf16x8;
typedef __attribute__((ext_vector_type(4))) float  f32x4;

__device__ __forceinline__ float bf2f(u16 h) {
  union { u32 u; float f; } c; c.u = ((u32)h) << 16; return c.f;
}
__device__ __forceinline__ float u2f(u32 u) {
  union { u32 u; float f; } c; c.u = u; return c.f;
}
__device__ __forceinline__ u16 f2bf(float f) {
  union { float f; u32 u; } c; c.f = f;
  u32 u = c.u;
  u += 0x7fffu + ((u >> 16) & 1u);   // round-to-nearest-even
  return (u16)(u >> 16);
}
__device__ __forceinline__ void async_copy16(const void* g, void* l) {
  __builtin_amdgcn_global_load_lds((const __attribute__((address_space(1))) void*)g,
                                   (__attribute__((address_space(3))) void*)l, 16, 0, 0);
}

// ---------------------------------------------------------------- zero ------
__global__ void zero_kernel(float* __restrict__ p) {
  *(float4*)&p[(size_t)(blockIdx.x * 256 + threadIdx.x) * 4] = float4{0.f, 0.f, 0.f, 0.f};
}

// ---------------------------------------------------------------- prep ------
// WT layout: [mat][n][k] bf16, mat in {Wr2, Ws2, Wr3, Ws3}
__global__ void prep_kernel(const float* __restrict__ Wr2, const float* __restrict__ Ws2,
                            const float* __restrict__ Wr3, const float* __restrict__ Ws3,
                            u16* __restrict__ WT) {
  const int mat = blockIdx.y;
  const int n = blockIdx.x;
  const int k = threadIdx.x;
  const float* W = (mat == 0) ? Wr2 : (mat == 1) ? Ws2 : (mat == 2) ? Wr3 : Ws3;
  WT[((size_t)mat << 16) + ((size_t)n << 8) + k] = f2bf(W[(size_t)k * 256 + n]);
}

// ---------------------------------------------------------------- csr -------
// Per-graph CSR, rows padded to multiples of 8. Cols stored PRE-SCALED by 32
// (<<5); pad col = 512<<5 = 16384 (zero row).
__global__ __launch_bounds__(256) void csr_kernel(const int* __restrict__ src,
                                                  const int* __restrict__ dst,
                                                  u16* __restrict__ csr_col,
                                                  u32* __restrict__ csr_off) {
  __shared__ u32 cnt[512];
  __shared__ u32 scan[512];
  __shared__ u32 poff[513];
  const int g = blockIdx.x, t = threadIdx.x;
  const int base = g * N_NODES, ebase = g * E_EDGES;
  for (int i = t; i < 512; i += 256) cnt[i] = 0;
  __syncthreads();
  for (int e = t; e < E_EDGES; e += 256)
    atomicAdd(&cnt[dst[ebase + e] - base], 1u);
  __syncthreads();
  for (int i = t; i < 512; i += 256) scan[i] = (cnt[i] + 7u) & ~7u;
  __syncthreads();
  #pragma unroll 1
  for (int d = 1; d < 512; d <<= 1) {
    const u32 v0 = (t >= d) ? scan[t - d] : 0u;
    const u32 v1 = scan[t + 256 - d];
    __syncthreads();
    if (t >= d) scan[t] += v0;
    scan[t + 256] += v1;
    __syncthreads();
  }
  if (t == 0) poff[0] = 0;
  for (int i = t; i < 512; i += 256) poff[i + 1] = scan[i];
  __syncthreads();
  for (int i = t; i < 513; i += 256) csr_off[(size_t)g * 513 + i] = poff[i];
  for (int i = t; i < 512; i += 256) {
    const u32 s = poff[i] + cnt[i], e2 = poff[i + 1];
    for (u32 k = s; k < e2; ++k) csr_col[(size_t)g * CSR_STRIDE + k] = 16384;
  }
  __syncthreads();
  for (int i = t; i < 512; i += 256) cnt[i] = poff[i];
  __syncthreads();
  for (int e = t; e < E_EDGES; e += 256) {
    const int d = dst[ebase + e] - base;
    const int s = src[ebase + e] - base;
    const u32 pos = atomicAdd(&cnt[d], 1u);
    csr_col[(size_t)g * CSR_STRIDE + pos] = (u16)(s << 5);
  }
}

// ---------------------------------------------------------------- conv1 -----
// Block (c,g): graph g, node half c. Cols <<5-scaled -> col = c32 >> 5.
__global__ __launch_bounds__(256) void conv1_kernel(const float* __restrict__ x,
                             const u16* __restrict__ csr_col, const u32* __restrict__ csr_off,
                             const float* __restrict__ Wr1, const float* __restrict__ Ws1,
                             const float* __restrict__ b1,
                             u16* __restrict__ H1, float* __restrict__ X1) {
  __shared__ float xs[513 * 4];        // +zero row 512
  __shared__ float aggs[N_NODES * 5];
  __shared__ __align__(16) u16 cols[CSR_STRIDE];
  __shared__ u32 offs[513];
  const int c = blockIdx.x;            // node half 0/1
  const int g = blockIdx.y;
  const int base = g * N_NODES;
  const int t = threadIdx.x;           // 256 threads

  for (int i = t; i < N_NODES; i += 256)
    *(float4*)&xs[i * 4] = *(const float4*)&x[(size_t)(base + i) * 4];
  if (t < 4) xs[512 * 4 + t] = 0.f;
  for (int i = t; i < CSR_STRIDE / 2; i += 256)
    ((u32*)cols)[i] = ((const u32*)(csr_col + (size_t)g * CSR_STRIDE))[i];
  for (int i = t; i < 513; i += 256) offs[i] = csr_off[(size_t)g * 513 + i];
  __syncthreads();

  #pragma unroll
  for (int nn = 0; nn < 2; ++nn) {
    const int i = t * 2 + nn;
    const u32 s0 = offs[i];
    const int nb = (int)((offs[i + 1] - s0) >> 3);
    float a0 = 0.f, a1 = 0.f, a2 = 0.f, a3 = 0.f;
    for (int b = 0; b < nb; ++b) {
      const uint4 cw = *(const uint4*)&cols[s0 + (u32)b * 8];
      const u32 ww[4] = {cw.x, cw.y, cw.z, cw.w};
      #pragma unroll
      for (int q = 0; q < 4; ++q) {
        const int ca = (int)((ww[q] & 0xffffu) >> 5);
        const int cb = (int)(ww[q] >> 21);
        const float4 va = *(const float4*)&xs[ca * 4];
        const float4 vb = *(const float4*)&xs[cb * 4];
        a0 += va.x + vb.x; a1 += va.y + vb.y;
        a2 += va.z + vb.z; a3 += va.w + vb.w;
      }
    }
    aggs[i * 5 + 0] = a0; aggs[i * 5 + 1] = a1;
    aggs[i * 5 + 2] = a2; aggs[i * 5 + 3] = a3;
  }
  __syncthreads();

  float wr[4], wsv[4];
  #pragma unroll
  for (int k = 0; k < 4; ++k) { wr[k] = Wr1[k * 256 + t]; wsv[k] = Ws1[k * 256 + t]; }
  const float bb = b1[t];
  float mx = 0.f, sm = 0.f;   // relu => >= 0
  const int nlo = c * 256;
  for (int n = nlo; n < nlo + 256; ++n) {
    float acc = bb;
    #pragma unroll
    for (int k = 0; k < 4; ++k) acc += aggs[n * 5 + k] * wr[k] + xs[n * 4 + k] * wsv[k];
    acc = fmaxf(acc, 0.f);
    H1[(size_t)(base + n) * D_DIM + t] = f2bf(acc);
    mx = fmaxf(mx, acc);
    sm += acc;
  }
  atomicMax((int*)&X1[(size_t)g * 512 + t], __float_as_int(mx));
  atomicAdd(&X1[(size_t)g * 512 + 256 + t], sm);   // raw sum; /512 in mlp
}

// ---------------------------------------------------------------- agg -------
// Gather segment_sum. Degree-sorted 4-row groups + 2-batch software pipeline
// (LOAD(b+1) issued before ACCUM(b)) + async_copy16 staging (linear LDS,
// AS=128 - within-row contiguous reads never bank-conflict).
__global__ __launch_bounds__(512) void agg_gather_kernel(const u16* __restrict__ H,
                                                         const u16* __restrict__ csr_col,
                                                         const u32* __restrict__ csr_off,
                                                         u16* __restrict__ AGG) {
  __shared__ __align__(16) u16 hs[513 * 128];          // 131,328 B (row 512 = zeros)
  __shared__ __align__(16) u16 cols[CSR_STRIDE + 8];   // 24,592 B (+pad batch)
  __shared__ u32 offs[513];                            // 2,052 B
  __shared__ u32 swork[512];                           // 2,048 B  (~160,020 total)
  const int c = blockIdx.x;          // feature chunk (128 feats)
  const int g = blockIdx.y;
  const int base = g * N_NODES;
  const int t = threadIdx.x;         // 512 threads
  const int w = t >> 6, lane = t & 63;

  // async staging: hs rows w*64..w*64+63 (16 instrs/wave, 4 rows each)
  {
    const int r0w = w * 64;
    const u16* Hsrc = &H[(size_t)(base + r0w + (lane >> 4)) * D_DIM + c * 128 + (lane & 15) * 8];
    #pragma unroll
    for (int i = 0; i < 16; ++i)
      async_copy16(Hsrc + (size_t)i * 4 * D_DIM, &hs[(r0w + i * 4) * 128]);
    const u16* Csrc = &csr_col[(size_t)g * CSR_STRIDE + w * 1536 + lane * 8];
    #pragma unroll
    for (int i = 0; i < 3; ++i)
      async_copy16(Csrc + i * 512, &cols[(w * 3 + i) * 512]);
  }
  if (t < 32) *(uint2*)&hs[512 * 128 + t * 4] = uint2{0u, 0u};   // zero row
  if (t < 8) cols[CSR_STRIDE + t] = 16384;                       // pad batch
  for (int i = t; i < 513; i += 512) offs[i] = csr_off[(size_t)g * 513 + i];
  asm volatile("s_waitcnt vmcnt(0)" ::: "memory");
  __syncthreads();

  // per-wave degree sort: key = (nb<<16)|row, bitonic ascending over 64 lanes
  {
    const int row = (w << 6) + lane;
    const u32 s0 = offs[row];
    const u32 nb = (offs[row + 1] - s0) >> 3;
    u32 key = (nb << 16) | (u32)row;
    #pragma unroll
    for (int k = 2; k <= 64; k <<= 1) {
      #pragma unroll
      for (int jj = k >> 1; jj > 0; jj >>= 1) {
        const u32 o = (u32)__shfl_xor((int)key, jj);
        const bool up = ((lane & k) == 0);
        const bool lower = ((lane & jj) == 0);
        const u32 mn = min(key, o), mx = max(key, o);
        key = (up == lower) ? mn : mx;
      }
    }
    swork[(w << 6) + lane] = key;
  }
  __syncthreads();

  const int h2 = lane >> 5, fl = lane & 31;
  const int i0w = w << 6;
  const u32 padu = (u32)(CSR_STRIDE + h2 * 4);
  const u32 h2o = (u32)(h2 * 4);
  #pragma unroll 1
  for (int j = 0; j < 16; ++j) {
    const uint4 kw = *(const uint4*)&swork[i0w + j * 4];
    const int rw[4] = {(int)(kw.x & 0xffffu), (int)(kw.y & 0xffffu),
                       (int)(kw.z & 0xffffu), (int)(kw.w & 0xffffu)};
    const int nb[4] = {(int)(kw.x >> 16), (int)(kw.y >> 16),
                       (int)(kw.z >> 16), (int)(kw.w >> 16)};
    const int nbmax = nb[3];           // sorted ascending -> slot 3 is max
    u32 cu[4];
    #pragma unroll
    for (int q = 0; q < 4; ++q) cu[q] = offs[rw[q]] + h2o;
    float a[4][4];
    #pragma unroll
    for (int q = 0; q < 4; ++q) { a[q][0] = 0.f; a[q][1] = 0.f; a[q][2] = 0.f; a[q][3] = 0.f; }

    uint2 dA[16], dB[16];
    auto LOAD = [&](uint2 (&d)[16], int b) {
      #pragma unroll
      for (int q = 0; q < 4; ++q) {
        const u32 u = (b < nb[q]) ? (cu[q] + (u32)b * 8u) : padu;
        const uint2 cw = *(const uint2*)&cols[u];
        const int e0 = (int)(cw.x & 0xffffu), e1 = (int)(cw.x >> 16);
        const int e2 = (int)(cw.y & 0xffffu), e3 = (int)(cw.y >> 16);
        d[q * 4 + 0] = *(const uint2*)&hs[(u32)(e0 + fl) << 2];
        d[q * 4 + 1] = *(const uint2*)&hs[(u32)(e1 + fl) << 2];
        d[q * 4 + 2] = *(const uint2*)&hs[(u32)(e2 + fl) << 2];
        d[q * 4 + 3] = *(const uint2*)&hs[(u32)(e3 + fl) << 2];
      }
    };
    auto ACCUM = [&](uint2 (&d)[16]) {
      #pragma unroll
      for (int q = 0; q < 4; ++q) {
        const uint2 d0 = d[q * 4 + 0], d1 = d[q * 4 + 1];
        const uint2 d2 = d[q * 4 + 2], d3 = d[q * 4 + 3];
        a[q][0] += (u2f(d0.x << 16) + u2f(d1.x << 16)) + (u2f(d2.x << 16) + u2f(d3.x << 16));
        a[q][1] += (u2f(d0.x & 0xffff0000u) + u2f(d1.x & 0xffff0000u))
                 + (u2f(d2.x & 0xffff0000u) + u2f(d3.x & 0xffff0000u));
        a[q][2] += (u2f(d0.y << 16) + u2f(d1.y << 16)) + (u2f(d2.y << 16) + u2f(d3.y << 16));
        a[q][3] += (u2f(d0.y & 0xffff0000u) + u2f(d1.y & 0xffff0000u))
                 + (u2f(d2.y & 0xffff0000u) + u2f(d3.y & 0xffff0000u));
      }
    };

    LOAD(dA, 0);
    #pragma unroll 1
    for (int b = 0; b < nbmax; b += 2) {
      if (b + 1 < nbmax) LOAD(dB, b + 1);
      ACCUM(dA);
      if (b + 2 < nbmax) LOAD(dA, b + 2);
      if (b + 1 < nbmax) ACCUM(dB);
    }

    #pragma unroll
    for (int q = 0; q < 4; ++q) {
      const float v0 = a[q][0] + __shfl_xor(a[q][0], 32);
      const float v1 = a[q][1] + __shfl_xor(a[q][1], 32);
      const float v2 = a[q][2] + __shfl_xor(a[q][2], 32);
      const float v3 = a[q][3] + __shfl_xor(a[q][3], 32);
      if (h2 == 0) {
        uint2 o;
        o.x = (u32)f2bf(v0) | ((u32)f2bf(v1) << 16);
        o.y = (u32)f2bf(v2) | ((u32)f2bf(v3) << 16);
        *(uint2*)&AGG[(size_t)(base + rw[q]) * D_DIM + c * 128 + fl * 4] = o;
      }
    }
  }
}

// ---------------------------------------------------------------- gemm ------
// Hout = relu(Amat @ Wr + Hmat @ Ws + bias). BM=256, 8 waves (4x2), dbuf
// async staging (3 asyncs/wave/stage), counted vmcnt(3), raw s_barrier.
// LDS 48 KB -> 2 blocks/CU.
__global__ __launch_bounds__(512) void gemm_kernel(const u16* __restrict__ Amat,
                                                   const u16* __restrict__ Hmat,
                                                   const u16* __restrict__ WrT,
                                                   const u16* __restrict__ WsT,
                                                   const float* __restrict__ bias,
                                                   u16* __restrict__ Hout,
                                                   float* __restrict__ x2pool,
                                                   float* __restrict__ score,
                                                   const float* __restrict__ pvec) {
  __shared__ __align__(16) u16 At[2][256 * 32];
  __shared__ __align__(16) u16 Bt[2][128 * 32];
  const int m0 = blockIdx.x * 256;
  const int n0 = blockIdx.y * 128;
  const int t = threadIdx.x;
  const int wid = t >> 6, lane = t & 63;
  const int wm = wid >> 1, wn = wid & 1;
  const int r16 = lane & 15, q0 = lane >> 4;

  f32x4 acc[4][4];
  const f32x4 zero = {0.f, 0.f, 0.f, 0.f};
  #pragma unroll
  for (int i = 0; i < 4; ++i)
    #pragma unroll
    for (int jj = 0; jj < 4; ++jj) acc[i][jj] = zero;

  const int srow_off = lane >> 2;
  const int sq = lane & 3;

  auto stage = [&](int s) {
    const int buf = s & 1;
    const int ph = s >> 3;
    const int kk = (s & 7) * 32;
    const u16* Ain = ph ? Hmat : Amat;
    const u16* Win = ph ? WsT : WrT;
    #pragma unroll
    for (int j = 0; j < 3; ++j) {
      const int chk = wid * 3 + j;
      if (chk < 16) {
        const int r = chk * 16 + srow_off;
        const int qsrc = sq ^ ((r >> 1) & 3);
        async_copy16(&Ain[(size_t)(m0 + r) * 256 + kk + qsrc * 8], &At[buf][chk * 512]);
      } else {
        const int ch = chk - 16;
        const int r = ch * 16 + srow_off;
        const int qsrc = sq ^ ((r >> 1) & 3);
        async_copy16(&Win[(size_t)(n0 + r) * 256 + kk + qsrc * 8], &Bt[buf][ch * 512]);
      }
    }
  };

  stage(0);
  #pragma unroll 1
  for (int s = 0; s < 16; ++s) {
    if (s < 15) {
      stage(s + 1);
      asm volatile("s_waitcnt vmcnt(3)" ::: "memory");
    } else {
      asm volatile("s_waitcnt vmcnt(0)" ::: "memory");
    }
    __builtin_amdgcn_s_barrier();
    const int buf = s & 1;
    bf16x8 aF[4], bF[4];
    #pragma unroll
    for (int mi = 0; mi < 4; ++mi) {
      const int arow = wm * 64 + mi * 16 + r16;
      const int qs = q0 ^ ((arow >> 1) & 3);
      aF[mi] = *(const bf16x8*)&At[buf][arow * 32 + qs * 8];
    }
    #pragma unroll
    for (int ni = 0; ni < 4; ++ni) {
      const int brow = wn * 64 + ni * 16 + r16;
      const int qs = q0 ^ ((brow >> 1) & 3);
      bF[ni] = *(const bf16x8*)&Bt[buf][brow * 32 + qs * 8];
    }
    #pragma unroll
    for (int mi = 0; mi < 4; ++mi)
      #pragma unroll
      for (int ni = 0; ni < 4; ++ni)
        acc[mi][ni] = __builtin_amdgcn_mfma_f32_16x16x32_bf16(aF[mi], bF[ni],
                                                              acc[mi][ni], 0, 0, 0);
    __builtin_amdgcn_s_barrier();
  }

  const bool do_x2 = (x2pool != nullptr);
  const bool do_sc = (score != nullptr);
  float colmax[4], colsum[4], pv[4], rpart[4][4];
  #pragma unroll
  for (int ni = 0; ni < 4; ++ni) { colmax[ni] = 0.f; colsum[ni] = 0.f; pv[ni] = 0.f; }
  #pragma unroll
  for (int mi = 0; mi < 4; ++mi)
    #pragma unroll
    for (int r = 0; r < 4; ++r) rpart[mi][r] = 0.f;
  if (do_sc) {
    #pragma unroll
    for (int ni = 0; ni < 4; ++ni) pv[ni] = pvec[n0 + wn * 64 + ni * 16 + r16];
  }

  // epilogue: C/D layout col = lane&15, row = (lane>>4)*4 + reg  [m89]
  #pragma unroll
  for (int mi = 0; mi < 4; ++mi) {
    const int growb = m0 + wm * 64 + mi * 16 + q0 * 4;
    #pragma unroll
    for (int ni = 0; ni < 4; ++ni) {
      const int gcol = n0 + wn * 64 + ni * 16 + r16;
      const float bv = bias[gcol];
      #pragma unroll
      for (int r = 0; r < 4; ++r) {
        float v = acc[mi][ni][r] + bv;
        v = fmaxf(v, 0.f);
        Hout[(size_t)(growb + r) * 256 + gcol] = f2bf(v);
        colmax[ni] = fmaxf(colmax[ni], v);
        colsum[ni] += v;
        rpart[mi][r] += v * pv[ni];
      }
    }
  }

  const int gg = m0 >> 9;   // 256-row tile never straddles a graph
  if (do_x2) {
    #pragma unroll
    for (int ni = 0; ni < 4; ++ni) {
      const int gcol = n0 + wn * 64 + ni * 16 + r16;
      float cm = colmax[ni], cs = colsum[ni];
      cm = fmaxf(cm, __shfl_xor(cm, 16));
      cm = fmaxf(cm, __shfl_xor(cm, 32));
      cs += __shfl_xor(cs, 16);
      cs += __shfl_xor(cs, 32);
      if (q0 == 0) {
        atomicMax((int*)&x2pool[(size_t)gg * 512 + gcol], __float_as_int(cm));
        atomicAdd(&x2pool[(size_t)gg * 512 + 256 + gcol], cs);
      }
    }
  }
  if (do_sc) {
    #pragma unroll
    for (int mi = 0; mi < 4; ++mi) {
      const int growb = m0 + wm * 64 + mi * 16 + q0 * 4;
      #pragma unroll
      for (int r = 0; r < 4; ++r) {
        float sp = rpart[mi][r];
        sp += __shfl_xor(sp, 1);
        sp += __shfl_xor(sp, 2);
        sp += __shfl_xor(sp, 4);
        sp += __shfl_xor(sp, 8);
        if (r16 == 0) atomicAdd(&score[growb + r], sp);
      }
    }
  }
}

// ---------------------------------------------------------------- sort ------
__global__ __launch_bounds__(256) void sort_kernel(const float* __restrict__ score,
                                                   const float* __restrict__ p,
                                                   u16* __restrict__ top_idx,
                                                   float* __restrict__ top_scale) {
  __shared__ float sval[N_NODES];
  __shared__ int sidx[N_NODES];
  __shared__ float wsum[4];
  const int g = blockIdx.x, t = threadIdx.x;

  float pvt = p[t];
  float sq2 = pvt * pvt;
  #pragma unroll
  for (int off = 32; off > 0; off >>= 1) sq2 += __shfl_down(sq2, off);
  if ((t & 63) == 0) wsum[t >> 6] = sq2;
  __syncthreads();
  const float inv_pn = 1.f / (sqrtf(wsum[0] + wsum[1] + wsum[2] + wsum[3]) + 1e-16f);

  for (int n = t; n < N_NODES; n += 256) {
    sval[n] = score[(size_t)g * 512 + n] * inv_pn;
    sidx[n] = n;
  }
  __syncthreads();

  for (int k = 2; k <= N_NODES; k <<= 1) {
    for (int jj = k >> 1; jj > 0; jj >>= 1) {
      const int i = ((t & ~(jj - 1)) << 1) | (t & (jj - 1));
      const int ix = i | jj;
      const bool dirDesc = ((i & k) == 0);
      const float vi = sval[i], vx = sval[ix];
      const int ii = sidx[i], ij = sidx[ix];
      const bool iAfter = (vi < vx) || (vi == vx && ii > ij);
      if (dirDesc ? iAfter : !iAfter) {
        sval[i] = vx; sval[ix] = vi;
        sidx[i] = ij; sidx[ix] = ii;
      }
      __syncthreads();
    }
  }

  for (int s = t; s < K_TOP; s += 256) {
    top_idx[(size_t)g * 416 + s] = (u16)sidx[s];
    top_scale[(size_t)g * 416 + s] = tanhf(sval[s]);
  }
}

// ---------------------------------------------------------------- x3 pool ---
__global__ __launch_bounds__(256) void x3_pool_kernel(const u16* __restrict__ H3,
                                                      const u16* __restrict__ top_idx,
                                                      const float* __restrict__ top_scale,
                                                      float* __restrict__ X3) {
  __shared__ u16 sidxL[416];
  __shared__ float ssclL[416];
  __shared__ float redm[32 * 65];
  __shared__ float reds[32 * 65];
  const int c = blockIdx.x;          // 0..3
  const int g = blockIdx.y;
  const int t = threadIdx.x;
  const int fl = t & 7, rg = t >> 3;

  for (int s = t; s < K_TOP; s += 256) {
    sidxL[s] = top_idx[(size_t)g * 416 + s];
    ssclL[s] = top_scale[(size_t)g * 416 + s];
  }
  __syncthreads();

  float mx[8], sm[8];
  #pragma unroll
  for (int j = 0; j < 8; ++j) { mx[j] = -1e30f; sm[j] = 0.f; }
  const size_t rowbase = (size_t)g * 512;
  for (int s = rg; s < K_TOP; s += 32) {
    const int row = sidxL[s];
    const float sc = ssclL[s];
    const uint4 d = *(const uint4*)&H3[(rowbase + row) * 256 + c * 64 + fl * 8];
    const u32 wv[4] = {d.x, d.y, d.z, d.w};
    #pragma unroll
    for (int q = 0; q < 4; ++q) {
      const float v0 = u2f(wv[q] << 16) * sc;
      const float v1 = u2f(wv[q] & 0xffff0000u) * sc;
      mx[q * 2] = fmaxf(mx[q * 2], v0); sm[q * 2] += v0;
      mx[q * 2 + 1] = fmaxf(mx[q * 2 + 1], v1); sm[q * 2 + 1] += v1;
    }
  }
  #pragma unroll
  for (int j = 0; j < 8; ++j) {
    redm[rg * 65 + fl * 8 + j] = mx[j];
    reds[rg * 65 + fl * 8 + j] = sm[j];
  }
  __syncthreads();
  for (int st = 16; st >= 1; st >>= 1) {
    if (rg < st) {
      #pragma unroll
      for (int j = 0; j < 8; ++j) {
        const int a = rg * 65 + fl * 8 + j, b = (rg + st) * 65 + fl * 8 + j;
        redm[a] = fmaxf(redm[a], redm[b]);
        reds[a] += reds[b];
      }
    }
    __syncthreads();
  }
  if (rg == 0) {
    #pragma unroll
    for (int j = 0; j < 8; ++j) {
      X3[(size_t)g * 512 + c * 64 + fl * 8 + j] = redm[fl * 8 + j];
      X3[(size_t)g * 512 + 256 + c * 64 + fl * 8 + j] = reds[fl * 8 + j] * (1.f / (float)K_TOP);
    }
  }
}

// ---------------------------------------------------------------- mlp -------
__global__ void mlp_kernel(const float* __restrict__ X1, const float* __restrict__ X2,
                           const float* __restrict__ X3,
                           const float* __restrict__ W1, const float* __restrict__ c1,
                           const float* __restrict__ W2, const float* __restrict__ c2,
                           const float* __restrict__ W3, const float* __restrict__ c3,
                           float* __restrict__ out) {
  __shared__ float zs[512];
  __shared__ float z1[256];
  __shared__ float z2[128];
  const int g = blockIdx.x, t = threadIdx.x;
  for (int k = t; k < 512; k += 256) {
    const float x1v = X1[(size_t)g * 512 + k];
    const float x2v = X2[(size_t)g * 512 + k];
    const float x3v = X3[(size_t)g * 512 + k];
    zs[k] = (k < 256) ? (x1v + x2v + x3v)
                      : (x1v * (1.f / 512.f) + x2v * (1.f / 512.f) + x3v);
  }
  __syncthreads();
  {
    float acc = c1[t];
    for (int k = 0; k < 512; ++k) acc += zs[k] * W1[(size_t)k * 256 + t];
    z1[t] = fmaxf(acc, 0.f);
  }
  __syncthreads();
  if (t < 128) {
    float acc = c2[t];
    for (int d = 0; d < 256; ++d) acc += z1[d] * W2[(size_t)d * 128 + t];
    z2[t] = fmaxf(acc, 0.f);
  }
  __syncthreads();
  if (t == 0) {
    float acc = c3[0];
    for (int e = 0; e < 128; ++e) acc += z2[e] * W3[e];
    out[g] = 1.f / (1.f + expf(-acc));
  }
}

// ---------------------------------------------------------------- launch ----
extern "C" void kernel_launch(void* const* d_in, const int* in_sizes, int n_in,
                              void* d_out, int out_size, void* d_ws, size_t ws_size,
                              hipStream_t stream) {
  (void)in_sizes; (void)n_in; (void)out_size; (void)ws_size;
  const float* x   = (const float*)d_in[0];
  const int* src   = (const int*)d_in[1];
  const int* dstp  = (const int*)d_in[2];
  const float* Wr1 = (const float*)d_in[3];
  const float* Ws1 = (const float*)d_in[4];
  const float* b1  = (const float*)d_in[5];
  const float* Wr2 = (const float*)d_in[6];
  const float* Ws2 = (const float*)d_in[7];
  const float* b2  = (const float*)d_in[8];
  const float* Wr3 = (const float*)d_in[9];
  const float* Ws3 = (const float*)d_in[10];
  const float* b3  = (const float*)d_in[11];
  const float* pat = (const float*)d_in[12];
  const float* W1  = (const float*)d_in[13];
  const float* c1  = (const float*)d_in[14];
  const float* W2  = (const float*)d_in[15];
  const float* c2  = (const float*)d_in[16];
  const float* W3  = (const float*)d_in[17];
  const float* c3  = (const float*)d_in[18];
  float* out = (float*)d_out;

  char* ws = (char*)d_ws;
  u16* hA  = (u16*)(ws);                 // 32 MB  (h1, later h3)
  u16* hB  = (u16*)(ws + 33554432);      // 32 MB  (h2)
  u16* AGG = (u16*)(ws + 67108864);      // 32 MB
  u16* WT  = (u16*)(ws + 100663296);     // 512 KB
  float* x1 = (float*)(ws + 101187584);  // 256 KB
  float* x2 = (float*)(ws + 101449728);  // 256 KB (contiguous after x1)
  float* x3 = (float*)(ws + 101711872);  // 256 KB
  u16* csr_col = (u16*)(ws + 101974016); // 3 MB (<<5-scaled; dead after agg#2)
  u32* csr_off = (u32*)(ws + 105119744); // 263 KB
  // aliases into dead csr_col region (used only after agg#2):
  float* score     = (float*)(ws + 101974016);            // 256 KB
  u16* top_idx     = (u16*)(ws + 101974016 + 262144);     // 104 KB
  float* top_scale = (float*)(ws + 101974016 + 372736);   // 208 KB

  prep_kernel<<<dim3(256, 4), dim3(256), 0, stream>>>(Wr2, Ws2, Wr3, Ws3, WT);
  csr_kernel<<<dim3(128), dim3(256), 0, stream>>>(src, dstp, csr_col, csr_off);
  zero_kernel<<<dim3(128), dim3(256), 0, stream>>>(x1);   // zeros x1 + x2 (contiguous)
  conv1_kernel<<<dim3(2, 128), dim3(256), 0, stream>>>(x, csr_col, csr_off, Wr1, Ws1, b1, hA, x1);

  agg_gather_kernel<<<dim3(2, 128), dim3(512), 0, stream>>>(hA, csr_col, csr_off, AGG);
  gemm_kernel<<<dim3(256, 2), dim3(512), 0, stream>>>(AGG, hA, WT, WT + 65536, b2, hB,
                                                      x2, nullptr, nullptr);

  agg_gather_kernel<<<dim3(2, 128), dim3(512), 0, stream>>>(hB, csr_col, csr_off, AGG);
  zero_kernel<<<dim3(64), dim3(256), 0, stream>>>(score);
  gemm_kernel<<<dim3(256, 2), dim3(512), 0, stream>>>(AGG, hB, WT + 131072, WT + 196608, b3, hA,
                                                      nullptr, score, pat);

  sort_kernel<<<dim3(128), dim3(256), 0, stream>>>(score, pat, top_idx, top_scale);
  x3_pool_kernel<<<dim3(4, 128), dim3(256), 0, stream>>>(hA, top_idx, top_scale, x3);
  mlp_kernel<<<dim3(128), dim3(256), 0, stream>>>(x1, x2, x3, W1, c1, W2, c2, W3, c3, out);
}